// Round 4
// baseline (727.261 us; speedup 1.0000x reference)
//
#include <hip/hip_runtime.h>

// ---------------------------------------------------------------------------
// DUPLEX GAT, round 4.
//   - dst-CSR build once (hist + parallel scan + fill with preseeded cursor).
//   - Per layer (both channels in each dispatch):
//       GEMM: fp32 reg-tiled, 2-phase K staging (32KB LDS -> 4 blocks/CU),
//             fused el/er epilogue, grid.y = channel.
//       gather: float4-per-lane; 32 lanes span a 128-float ft row
//               (global_load_dwordx4, 1KB/wave-load); 4 waves cover
//               4 edges/iter; LDS-staged softmax coefs; shfl combines.
// ---------------------------------------------------------------------------

struct GemmP { const float *X, *W, *al, *ar; float *Y, *el, *er; };
struct ChP   { const float *ft, *el, *er, *w, *bias; float *out; };

__global__ void hist_kernel(const int* __restrict__ dst, int* __restrict__ counts, int E) {
  int e = blockIdx.x * blockDim.x + threadIdx.x;
  if (e < E) atomicAdd(&counts[dst[e]], 1);
}

__global__ __launch_bounds__(256) void scan1_kernel(const int* __restrict__ counts,
                                                    int* __restrict__ incl,
                                                    int* __restrict__ bsum, int n) {
  __shared__ int lds[256];
  int i = blockIdx.x * 256 + threadIdx.x;
  int v = (i < n) ? counts[i] : 0;
  lds[threadIdx.x] = v;
  __syncthreads();
  for (int off = 1; off < 256; off <<= 1) {
    int t = (threadIdx.x >= off) ? lds[threadIdx.x - off] : 0;
    __syncthreads();
    lds[threadIdx.x] += t;
    __syncthreads();
  }
  if (i < n) incl[i] = lds[threadIdx.x];
  if (threadIdx.x == 255) bsum[blockIdx.x] = lds[255];
}

__global__ __launch_bounds__(256) void scan2_kernel(int* __restrict__ bsum, int nb) {
  __shared__ int lds[256];
  int carry = 0;
  for (int base = 0; base < nb; base += 256) {
    int i = base + threadIdx.x;
    int v = (i < nb) ? bsum[i] : 0;
    lds[threadIdx.x] = v;
    __syncthreads();
    for (int off = 1; off < 256; off <<= 1) {
      int t = (threadIdx.x >= off) ? lds[threadIdx.x - off] : 0;
      __syncthreads();
      lds[threadIdx.x] += t;
      __syncthreads();
    }
    if (i < nb) bsum[i] = carry + lds[threadIdx.x] - v;  // exclusive
    carry += lds[255];
    __syncthreads();
  }
}

__global__ void scan3_kernel(const int* __restrict__ counts, const int* __restrict__ incl,
                             const int* __restrict__ bsum_ex, int* __restrict__ offsets,
                             int n, int E) {
  int i = blockIdx.x * blockDim.x + threadIdx.x;
  if (i < n) offsets[i] = incl[i] - counts[i] + bsum_ex[i >> 8];
  if (i == 0) offsets[n] = E;
}

// cursor preseeded with offsets -> atomicAdd returns absolute position.
__global__ void fill_kernel(const int* __restrict__ src, const int* __restrict__ dst,
                            const float* __restrict__ exist, const float* __restrict__ am_exist,
                            int* __restrict__ cursor, int* __restrict__ csr_src,
                            float* __restrict__ w_am, float* __restrict__ w_ph, int E) {
  int e = blockIdx.x * blockDim.x + threadIdx.x;
  if (e >= E) return;
  int pos = atomicAdd(&cursor[dst[e]], 1);
  csr_src[pos] = src[e];
  w_am[pos] = am_exist[e];
  w_ph[pos] = exist[e];
}

// Y = X @ W (n x 128 @ 128 x 128, fp32), 2-phase K staging, fused el/er epilogue.
__global__ __launch_bounds__(256) void gemm_kernel(GemmP p0, GemmP p1, int n) {
  GemmP p = blockIdx.y ? p1 : p0;
  __shared__ float xs[64][128];  // xs[k][r], one 64-wide K phase
  int row0 = blockIdx.x << 7;
  int t = threadIdx.x;
  int tx = t & 15;  // cols tx*8..+7 (one head per thread)
  int ty = t >> 4;  // rows ty*8..+7
  const float4* W4 = (const float4*)p.W;
  float acc[8][8];
#pragma unroll
  for (int r = 0; r < 8; ++r)
#pragma unroll
    for (int c = 0; c < 8; ++c) acc[r][c] = 0.f;

  int r_st = t & 127;          // staging row
  int row_st = row0 + r_st;
  bool ok = row_st < n;
#pragma unroll
  for (int ph = 0; ph < 2; ++ph) {
    __syncthreads();  // protect previous phase's reads
#pragma unroll
    for (int i = 0; i < 8; ++i) {
      int idx = t + (i << 8);
      int r = idx & 127;
      int k4 = idx >> 7;  // 0..15
      float4 v = make_float4(0.f, 0.f, 0.f, 0.f);
      if (row0 + r < n) v = *(const float4*)(p.X + (size_t)(row0 + r) * 128 + (ph << 6) + (k4 << 2));
      xs[(k4 << 2) + 0][r] = v.x;
      xs[(k4 << 2) + 1][r] = v.y;
      xs[(k4 << 2) + 2][r] = v.z;
      xs[(k4 << 2) + 3][r] = v.w;
    }
    __syncthreads();
#pragma unroll 4
    for (int k = 0; k < 64; ++k) {
      int kg = (ph << 6) + k;
      float4 w0 = W4[(kg << 5) + (tx << 1)];
      float4 w1 = W4[(kg << 5) + (tx << 1) + 1];
      float4 x0 = *(const float4*)&xs[k][(ty << 3)];
      float4 x1 = *(const float4*)&xs[k][(ty << 3) + 4];
      float xv[8] = {x0.x, x0.y, x0.z, x0.w, x1.x, x1.y, x1.z, x1.w};
      float wv[8] = {w0.x, w0.y, w0.z, w0.w, w1.x, w1.y, w1.z, w1.w};
#pragma unroll
      for (int r = 0; r < 8; ++r)
#pragma unroll
        for (int c = 0; c < 8; ++c) acc[r][c] = fmaf(xv[r], wv[c], acc[r][c]);
    }
  }
#pragma unroll
  for (int r = 0; r < 8; ++r) {
    int row = row0 + (ty << 3) + r;
    if (row < n) {
      float4* yp = (float4*)(p.Y + (size_t)row * 128 + (tx << 3));
      yp[0] = make_float4(acc[r][0], acc[r][1], acc[r][2], acc[r][3]);
      yp[1] = make_float4(acc[r][4], acc[r][5], acc[r][6], acc[r][7]);
    }
  }
  // ---- fused el/er epilogue ----
  float al_v[8], ar_v[8];
  {
    const float4* al4 = (const float4*)p.al;
    const float4* ar4 = (const float4*)p.ar;
    float4 a0 = al4[tx * 2], a1 = al4[tx * 2 + 1];
    float4 r0 = ar4[tx * 2], r1 = ar4[tx * 2 + 1];
    al_v[0] = a0.x; al_v[1] = a0.y; al_v[2] = a0.z; al_v[3] = a0.w;
    al_v[4] = a1.x; al_v[5] = a1.y; al_v[6] = a1.z; al_v[7] = a1.w;
    ar_v[0] = r0.x; ar_v[1] = r0.y; ar_v[2] = r0.z; ar_v[3] = r0.w;
    ar_v[4] = r1.x; ar_v[5] = r1.y; ar_v[6] = r1.z; ar_v[7] = r1.w;
  }
  __syncthreads();  // reuse xs as reduction scratch (needs 17.4KB <= 32KB)
  float* redl = &xs[0][0];        // [128][17]
  float* redr = redl + 128 * 17;  // [128][17]
#pragma unroll
  for (int r = 0; r < 8; ++r) {
    float pl = 0.f, pr = 0.f;
#pragma unroll
    for (int c = 0; c < 8; ++c) {
      pl = fmaf(acc[r][c], al_v[c], pl);
      pr = fmaf(acc[r][c], ar_v[c], pr);
    }
    redl[((ty << 3) + r) * 17 + tx] = pl;
    redr[((ty << 3) + r) * 17 + tx] = pr;
  }
  __syncthreads();
  if (t < 128 && ok) {
    float s[4], q[4];
#pragma unroll
    for (int h = 0; h < 4; ++h) {
      int b = r_st * 17 + h * 4;
      s[h] = redl[b] + redl[b + 1] + redl[b + 2] + redl[b + 3];
      q[h] = redr[b] + redr[b + 1] + redr[b + 2] + redr[b + 3];
    }
    *(float4*)(p.el + (size_t)row_st * 4) = make_float4(s[0], s[1], s[2], s[3]);
    *(float4*)(p.er + (size_t)row_st * 4) = make_float4(q[0], q[1], q[2], q[3]);
  }
}

// One node per 256-thr block. Waves 0-1: channel c0, waves 2-3: channel c1.
// Lane layout: j4 = lane&31 (float4 feature chunk), half = lane>>5;
// edge offset eo = (wave&1)*2 + half -> 4 edges in flight per k-step.
template <int LAYER>
__global__ __launch_bounds__(256) void gather_kernel(ChP c0, ChP c1,
                                                     const int* __restrict__ offs,
                                                     const int* __restrict__ csr_src, int n) {
  int t = threadIdx.x;
  int ch = t >> 7;
  ChP P = ch ? c1 : c0;
  int node = blockIdx.x;
  // staging ids (coef producers): 2 threads per (channel, edge-slot)
  int se = (t >> 1) & 63;
  int hp = t & 1;
  float2 er2 = *(const float2*)(P.er + (size_t)node * 4 + hp * 2);
  // compute ids
  int lane = t & 63;
  int w = t >> 6;
  int half = lane >> 5;
  int j4 = lane & 31;
  int eo = ((w & 1) << 1) | half;
  int h = j4 >> 3;

  __shared__ int s_src[64];
  __shared__ float s_coef[2][64][4];
  __shared__ float s_lred[2][4][64];
  __shared__ float s_comb[2][32][4];

  int start = offs[node], end = offs[node + 1];
  float lp0 = 0.f, lp1 = 0.f;
  float4 acc = make_float4(0.f, 0.f, 0.f, 0.f);
  const float* ftp = P.ft + (size_t)j4 * 4;

  for (int base = start; base < end; base += 64) {
    int cnt = min(64, end - base);
    __syncthreads();  // protect s_src/s_coef from previous chunk's readers
    if (se < cnt) {
      int s = csr_src[base + se];
      if (t < 128 && hp == 0) s_src[se] = s;
      float wgt = P.w[base + se];
      float2 el2 = *(const float2*)(P.el + (size_t)s * 4 + hp * 2);
      float e0 = el2.x + er2.x; e0 = (e0 > 0.f) ? e0 : 0.2f * e0;
      float e1 = el2.y + er2.y; e1 = (e1 > 0.f) ? e1 : 0.2f * e1;
      float x0 = __expf(e0), x1 = __expf(e1);
      lp0 += x0; lp1 += x1;
      s_coef[ch][se][hp * 2 + 0] = x0 * wgt;
      s_coef[ch][se][hp * 2 + 1] = x1 * wgt;
    }
    __syncthreads();
#pragma unroll 2
    for (int k = 0; k < cnt; k += 4) {
      int kk = k + eo;
      if (kk < cnt) {
        int s = s_src[kk];
        float c = s_coef[ch][kk][h];
        float4 f = *(const float4*)(ftp + (size_t)s * 128);
        acc.x = fmaf(c, f.x, acc.x);
        acc.y = fmaf(c, f.y, acc.y);
        acc.z = fmaf(c, f.z, acc.z);
        acc.w = fmaf(c, f.w, acc.w);
      }
    }
  }
  // denominator l[ch][h]
  __syncthreads();
  s_lred[ch][hp * 2 + 0][se] = lp0;
  s_lred[ch][hp * 2 + 1][se] = lp1;
  __syncthreads();
  float l = 0.f;
  const float4* lr4 = (const float4*)&s_lred[ch][h][0];
#pragma unroll
  for (int i = 0; i < 16; ++i) {
    float4 q = lr4[i];
    l += q.x + q.y + q.z + q.w;
  }
  float rl = 1.f / fmaxf(l, 1e-9f);
  // combine half-waves (edges eo, eo^1)
  acc.x += __shfl_xor(acc.x, 32);
  acc.y += __shfl_xor(acc.y, 32);
  acc.z += __shfl_xor(acc.z, 32);
  acc.w += __shfl_xor(acc.w, 32);
  // combine wave pairs: odd wave publishes, even wave accumulates
  if ((w & 1) && half == 0) *(float4*)&s_comb[ch][j4][0] = acc;
  __syncthreads();
  if (!(w & 1) && half == 0) {
    float4 o = *(const float4*)&s_comb[ch][j4][0];
    float4 b4 = *(const float4*)(P.bias + j4 * 4);
    float4 v;
    v.x = fmaf(acc.x + o.x, rl, b4.x);
    v.y = fmaf(acc.y + o.y, rl, b4.y);
    v.z = fmaf(acc.z + o.z, rl, b4.z);
    v.w = fmaf(acc.w + o.w, rl, b4.w);
    if (LAYER == 0) {
      v.x = fmaxf(v.x, 0.f); v.y = fmaxf(v.y, 0.f);
      v.z = fmaxf(v.z, 0.f); v.w = fmaxf(v.w, 0.f);
      *(float4*)(P.out + (size_t)node * 128 + j4 * 4) = v;
    } else {
      // mean over 4 heads: h = j4>>3, so xor 8 and 16 sum across heads
      v.x += __shfl_xor(v.x, 8);  v.y += __shfl_xor(v.y, 8);
      v.z += __shfl_xor(v.z, 8);  v.w += __shfl_xor(v.w, 8);
      v.x += __shfl_xor(v.x, 16); v.y += __shfl_xor(v.y, 16);
      v.z += __shfl_xor(v.z, 16); v.w += __shfl_xor(v.w, 16);
      if (j4 < 8) {
        *(float4*)(P.out + (size_t)node * 32 + j4 * 4) =
            make_float4(0.25f * v.x, 0.25f * v.y, 0.25f * v.z, 0.25f * v.w);
      }
    }
  }
}

extern "C" void kernel_launch(void* const* d_in, const int* in_sizes, int n_in,
                              void* d_out, int out_size, void* d_ws, size_t ws_size,
                              hipStream_t stream) {
  const float* x_am = (const float*)d_in[0];
  const float* x_ph = (const float*)d_in[1];
  const float* exist = (const float*)d_in[2];
  const float* am_exist = (const float*)d_in[3];
  const int* src = (const int*)d_in[4];
  const int* dst = (const int*)d_in[5];
  const float* W0a = (const float*)d_in[6];
  const float* al0a = (const float*)d_in[7];
  const float* ar0a = (const float*)d_in[8];
  const float* b0a = (const float*)d_in[9];
  const float* W0p = (const float*)d_in[10];
  const float* al0p = (const float*)d_in[11];
  const float* ar0p = (const float*)d_in[12];
  const float* b0p = (const float*)d_in[13];
  const float* W1a = (const float*)d_in[14];
  const float* al1a = (const float*)d_in[15];
  const float* ar1a = (const float*)d_in[16];
  const float* b1a = (const float*)d_in[17];
  const float* W1p = (const float*)d_in[18];
  const float* al1p = (const float*)d_in[19];
  const float* ar1p = (const float*)d_in[20];
  const float* b1p = (const float*)d_in[21];

  int n = in_sizes[0] / 128;  // 50000
  int E = in_sizes[2];        // 800000
  int N_pad = (n + 255) & ~255;
  int nb = (n + 255) / 256;
  int NB_pad = (nb + 63) & ~63;

  size_t szN = (size_t)N_pad * 4;
  size_t szOffs = (size_t)(N_pad + 8) * 4;
  size_t szE = (size_t)E * 4;
  size_t szFt = (size_t)n * 128 * 4;
  size_t szEl = (size_t)N_pad * 4 * 4;

  auto rnd = [](size_t b) { return (b + 255) & ~(size_t)255; };
  size_t fixed = 3 * rnd(szN) + rnd((size_t)NB_pad * 4) + rnd(szOffs) + 3 * rnd(szE) +
                 4 * rnd(szEl);
  bool dual = ws_size >= fixed + 4 * rnd(szFt);

  char* p = (char*)d_ws;
  auto take = [&](size_t b) { char* q = p; p += (b + 255) & ~(size_t)255; return q; };
  int* counts = (int*)take(szN);
  int* cursor = (int*)take(szN);
  int* incl = (int*)take(szN);
  int* bsum = (int*)take((size_t)NB_pad * 4);
  int* offs = (int*)take(szOffs);
  int* csr_src = (int*)take(szE);
  float* w_am = (float*)take(szE);
  float* w_ph = (float*)take(szE);
  float* el_am = (float*)take(szEl);
  float* el_ph = (float*)take(szEl);
  float* er_am = (float*)take(szEl);
  float* er_ph = (float*)take(szEl);
  float* ft_am = (float*)take(szFt);
  float* ft_ph = dual ? (float*)take(szFt) : ft_am;
  float* hb_am = (float*)take(szFt);
  float* hb_ph = dual ? (float*)take(szFt) : hb_am;

  float* out_am = (float*)d_out;
  float* out_ph = out_am + (size_t)n * 32;

  // ---- CSR build ----
  hipMemsetAsync(counts, 0, szN, stream);
  hist_kernel<<<(E + 255) / 256, 256, 0, stream>>>(dst, counts, E);
  scan1_kernel<<<nb, 256, 0, stream>>>(counts, incl, bsum, n);
  scan2_kernel<<<1, 256, 0, stream>>>(bsum, nb);
  scan3_kernel<<<nb, 256, 0, stream>>>(counts, incl, bsum, offs, n, E);
  hipMemcpyAsync(cursor, offs, szN, hipMemcpyDeviceToDevice, stream);
  fill_kernel<<<(E + 255) / 256, 256, 0, stream>>>(src, dst, exist, am_exist,
                                                   cursor, csr_src, w_am, w_ph, E);

  int gg = (n + 127) / 128;
  GemmP g0a{x_am, W0a, al0a, ar0a, ft_am, el_am, er_am};
  GemmP g0p{x_ph, W0p, al0p, ar0p, ft_ph, el_ph, er_ph};
  GemmP g1a{hb_am, W1a, al1a, ar1a, ft_am, el_am, er_am};
  GemmP g1p{hb_ph, W1p, al1p, ar1p, ft_ph, el_ph, er_ph};
  ChP c0a{ft_am, el_am, er_am, w_am, b0a, hb_am};
  ChP c0p{ft_ph, el_ph, er_ph, w_ph, b0p, hb_ph};
  ChP c1a{ft_am, el_am, er_am, w_am, b1a, out_am};
  ChP c1p{ft_ph, el_ph, er_ph, w_ph, b1p, out_ph};

  if (dual) {
    gemm_kernel<<<dim3(gg, 2), 256, 0, stream>>>(g0a, g0p, n);
    gather_kernel<0><<<n, 256, 0, stream>>>(c0a, c0p, offs, csr_src, n);
    gemm_kernel<<<dim3(gg, 2), 256, 0, stream>>>(g1a, g1p, n);
    gather_kernel<1><<<n, 256, 0, stream>>>(c1a, c1p, offs, csr_src, n);
  } else {
    // sequential fallback: both halves run the same channel (duplicate
    // identical writes, benign); buffers aliased above.
    gemm_kernel<<<dim3(gg, 2), 256, 0, stream>>>(g0a, g0a, n);
    gather_kernel<0><<<n, 256, 0, stream>>>(c0a, c0a, offs, csr_src, n);
    gemm_kernel<<<dim3(gg, 2), 256, 0, stream>>>(g1a, g1a, n);
    gather_kernel<1><<<n, 256, 0, stream>>>(c1a, c1a, offs, csr_src, n);
    gemm_kernel<<<dim3(gg, 2), 256, 0, stream>>>(g0p, g0p, n);
    gather_kernel<0><<<n, 256, 0, stream>>>(c0p, c0p, offs, csr_src, n);
    gemm_kernel<<<dim3(gg, 2), 256, 0, stream>>>(g1p, g1p, n);
    gather_kernel<1><<<n, 256, 0, stream>>>(c1p, c1p, offs, csr_src, n);
  }
}

// Round 5
// 628.175 us; speedup vs baseline: 1.1577x; 1.1577x over previous
//
#include <hip/hip_runtime.h>

// ---------------------------------------------------------------------------
// DUPLEX GAT, round 5.
//   - dst-CSR build once: hist + parallel scan + fill (packed int4 edge recs,
//     cursor preseeded from offsets).
//   - Per layer (both channels per dispatch):
//       GEMM: fp32 reg-tiled, 2-phase K staging (32KB LDS), fused el/er
//             epilogue, grid.y = channel.
//       gather: wave-per-edge; src is wave-uniform (readfirstlane -> scalar
//               base), 64 lanes x float2 = 512B/load; LDS-staged softmax
//               coefs (stride-5 pad, conflict-free); shfl-butterfly
//               denominator; 4 edges in flight per wave.
// ---------------------------------------------------------------------------

struct GemmP { const float *X, *W, *al, *ar; float *Y, *el, *er; };
struct ChP   { const float *ft, *el, *er, *bias; float *out; };

__global__ void hist_kernel(const int* __restrict__ dst, int* __restrict__ counts, int E) {
  int e = blockIdx.x * blockDim.x + threadIdx.x;
  if (e < E) atomicAdd(&counts[dst[e]], 1);
}

__global__ __launch_bounds__(256) void scan1_kernel(const int* __restrict__ counts,
                                                    int* __restrict__ incl,
                                                    int* __restrict__ bsum, int n) {
  __shared__ int lds[256];
  int i = blockIdx.x * 256 + threadIdx.x;
  int v = (i < n) ? counts[i] : 0;
  lds[threadIdx.x] = v;
  __syncthreads();
  for (int off = 1; off < 256; off <<= 1) {
    int t = (threadIdx.x >= off) ? lds[threadIdx.x - off] : 0;
    __syncthreads();
    lds[threadIdx.x] += t;
    __syncthreads();
  }
  if (i < n) incl[i] = lds[threadIdx.x];
  if (threadIdx.x == 255) bsum[blockIdx.x] = lds[255];
}

__global__ __launch_bounds__(256) void scan2_kernel(int* __restrict__ bsum, int nb) {
  __shared__ int lds[256];
  int carry = 0;
  for (int base = 0; base < nb; base += 256) {
    int i = base + threadIdx.x;
    int v = (i < nb) ? bsum[i] : 0;
    lds[threadIdx.x] = v;
    __syncthreads();
    for (int off = 1; off < 256; off <<= 1) {
      int t = (threadIdx.x >= off) ? lds[threadIdx.x - off] : 0;
      __syncthreads();
      lds[threadIdx.x] += t;
      __syncthreads();
    }
    if (i < nb) bsum[i] = carry + lds[threadIdx.x] - v;  // exclusive
    carry += lds[255];
    __syncthreads();
  }
}

__global__ void scan3_kernel(const int* __restrict__ counts, const int* __restrict__ incl,
                             const int* __restrict__ bsum_ex, int* __restrict__ offsets,
                             int n, int E) {
  int i = blockIdx.x * blockDim.x + threadIdx.x;
  if (i < n) offsets[i] = incl[i] - counts[i] + bsum_ex[i >> 8];
  if (i == 0) offsets[n] = E;
}

// cursor preseeded with offsets -> atomicAdd returns absolute position.
// Packed edge record: {src, w_am bits, w_ph bits, 0} -> one dwordx4 scatter.
__global__ void fill_kernel(const int* __restrict__ src, const int* __restrict__ dst,
                            const float* __restrict__ exist, const float* __restrict__ am_exist,
                            int* __restrict__ cursor, int4* __restrict__ edge16, int E) {
  int e = blockIdx.x * blockDim.x + threadIdx.x;
  if (e >= E) return;
  int pos = atomicAdd(&cursor[dst[e]], 1);
  edge16[pos] = make_int4(src[e], __float_as_int(am_exist[e]), __float_as_int(exist[e]), 0);
}

// Y = X @ W (n x 128 @ 128 x 128, fp32), 2-phase K staging, fused el/er epilogue.
__global__ __launch_bounds__(256) void gemm_kernel(GemmP p0, GemmP p1, int n) {
  GemmP p = blockIdx.y ? p1 : p0;
  __shared__ float xs[64][128];  // xs[k][r], one 64-wide K phase
  int row0 = blockIdx.x << 7;
  int t = threadIdx.x;
  int tx = t & 15;  // cols tx*8..+7 (one head per thread)
  int ty = t >> 4;  // rows ty*8..+7
  const float4* W4 = (const float4*)p.W;
  float acc[8][8];
#pragma unroll
  for (int r = 0; r < 8; ++r)
#pragma unroll
    for (int c = 0; c < 8; ++c) acc[r][c] = 0.f;

  int r_st = t & 127;  // staging/epilogue row
  int row_st = row0 + r_st;
  bool ok = row_st < n;
#pragma unroll
  for (int ph = 0; ph < 2; ++ph) {
    __syncthreads();
#pragma unroll
    for (int i = 0; i < 8; ++i) {
      int idx = t + (i << 8);
      int r = idx & 127;
      int k4 = idx >> 7;  // 0..15
      float4 v = make_float4(0.f, 0.f, 0.f, 0.f);
      if (row0 + r < n)
        v = *(const float4*)(p.X + (size_t)(row0 + r) * 128 + (ph << 6) + (k4 << 2));
      xs[(k4 << 2) + 0][r] = v.x;
      xs[(k4 << 2) + 1][r] = v.y;
      xs[(k4 << 2) + 2][r] = v.z;
      xs[(k4 << 2) + 3][r] = v.w;
    }
    __syncthreads();
#pragma unroll 4
    for (int k = 0; k < 64; ++k) {
      int kg = (ph << 6) + k;
      float4 w0 = W4[(kg << 5) + (tx << 1)];
      float4 w1 = W4[(kg << 5) + (tx << 1) + 1];
      float4 x0 = *(const float4*)&xs[k][(ty << 3)];
      float4 x1 = *(const float4*)&xs[k][(ty << 3) + 4];
      float xv[8] = {x0.x, x0.y, x0.z, x0.w, x1.x, x1.y, x1.z, x1.w};
      float wv[8] = {w0.x, w0.y, w0.z, w0.w, w1.x, w1.y, w1.z, w1.w};
#pragma unroll
      for (int r = 0; r < 8; ++r)
#pragma unroll
        for (int c = 0; c < 8; ++c) acc[r][c] = fmaf(xv[r], wv[c], acc[r][c]);
    }
  }
#pragma unroll
  for (int r = 0; r < 8; ++r) {
    int row = row0 + (ty << 3) + r;
    if (row < n) {
      float4* yp = (float4*)(p.Y + (size_t)row * 128 + (tx << 3));
      yp[0] = make_float4(acc[r][0], acc[r][1], acc[r][2], acc[r][3]);
      yp[1] = make_float4(acc[r][4], acc[r][5], acc[r][6], acc[r][7]);
    }
  }
  // ---- fused el/er epilogue ----
  float al_v[8], ar_v[8];
  {
    const float4* al4 = (const float4*)p.al;
    const float4* ar4 = (const float4*)p.ar;
    float4 a0 = al4[tx * 2], a1 = al4[tx * 2 + 1];
    float4 r0 = ar4[tx * 2], r1 = ar4[tx * 2 + 1];
    al_v[0] = a0.x; al_v[1] = a0.y; al_v[2] = a0.z; al_v[3] = a0.w;
    al_v[4] = a1.x; al_v[5] = a1.y; al_v[6] = a1.z; al_v[7] = a1.w;
    ar_v[0] = r0.x; ar_v[1] = r0.y; ar_v[2] = r0.z; ar_v[3] = r0.w;
    ar_v[4] = r1.x; ar_v[5] = r1.y; ar_v[6] = r1.z; ar_v[7] = r1.w;
  }
  __syncthreads();  // reuse xs as reduction scratch (17.4KB <= 32KB)
  float* redl = &xs[0][0];        // [128][17]
  float* redr = redl + 128 * 17;  // [128][17]
#pragma unroll
  for (int r = 0; r < 8; ++r) {
    float pl = 0.f, pr = 0.f;
#pragma unroll
    for (int c = 0; c < 8; ++c) {
      pl = fmaf(acc[r][c], al_v[c], pl);
      pr = fmaf(acc[r][c], ar_v[c], pr);
    }
    redl[((ty << 3) + r) * 17 + tx] = pl;
    redr[((ty << 3) + r) * 17 + tx] = pr;
  }
  __syncthreads();
  if (t < 128 && ok) {
    float s[4], q[4];
#pragma unroll
    for (int h = 0; h < 4; ++h) {
      int b = r_st * 17 + h * 4;
      s[h] = redl[b] + redl[b + 1] + redl[b + 2] + redl[b + 3];
      q[h] = redr[b] + redr[b + 1] + redr[b + 2] + redr[b + 3];
    }
    *(float4*)(p.el + (size_t)row_st * 4) = make_float4(s[0], s[1], s[2], s[3]);
    *(float4*)(p.er + (size_t)row_st * 4) = make_float4(q[0], q[1], q[2], q[3]);
  }
}

// One node per 256-thr block. Waves 0-1: channel 0, waves 2-3: channel 1.
// Each wave processes whole edges (64 lanes x float2 span the 128-feat row);
// the 2 waves of a channel split edges even/odd. src is wave-uniform ->
// scalar base loads. Coefs exp(e)*w staged in LDS per 64-edge chunk.
template <int LAYER>
__global__ __launch_bounds__(256) void gather_kernel(ChP c0, ChP c1,
                                                     const int* __restrict__ offs,
                                                     const int4* __restrict__ edge16, int n) {
  int t = threadIdx.x;
  int ch = t >> 7;
  int lane = t & 63;
  int w2 = (t >> 6) & 1;  // wave within channel
  ChP P = ch ? c1 : c0;
  int node = blockIdx.x;
  // staging ids: 2 threads (hp=0,1) per (channel, edge slot se)
  int se = (t >> 1) & 63;
  int hp = t & 1;
  float2 er2 = *(const float2*)(P.er + (size_t)node * 4 + hp * 2);
  int hh = lane >> 4;  // head of this lane's feature pair (j = lane*2, lane*2+1)

  __shared__ int s_src[64];
  __shared__ float s_coef[2][64][5];  // stride 5: conflict-free staging stores
  __shared__ float s_l[2][2][4];
  __shared__ float s_part[2][128];

  int start = offs[node], end = offs[node + 1];
  float lp0 = 0.f, lp1 = 0.f;     // partial denominators, heads hp*2, hp*2+1
  float acc0 = 0.f, acc1 = 0.f;   // features j = lane*2, lane*2+1

  for (int base = start; base < end; base += 64) {
    int cnt = min(64, end - base);
    __syncthreads();  // protect LDS from previous chunk's readers
    if (se < cnt) {
      int4 ed = edge16[base + se];
      int s = ed.x;
      if (ch == 0 && hp == 0) s_src[se] = s;
      float wgt = __int_as_float(ch ? ed.z : ed.y);
      float2 el2 = *(const float2*)(P.el + (size_t)s * 4 + hp * 2);
      float e0 = el2.x + er2.x; e0 = (e0 > 0.f) ? e0 : 0.2f * e0;
      float e1 = el2.y + er2.y; e1 = (e1 > 0.f) ? e1 : 0.2f * e1;
      float x0 = __expf(e0), x1 = __expf(e1);
      lp0 += x0; lp1 += x1;
      s_coef[ch][se][hp * 2 + 0] = x0 * wgt;
      s_coef[ch][se][hp * 2 + 1] = x1 * wgt;
    }
    __syncthreads();
    const float* ftp = P.ft + lane * 2;
    int k = w2;
    for (; k + 6 < cnt; k += 8) {  // 4 edges in flight per wave
      int s0 = __builtin_amdgcn_readfirstlane(s_src[k]);
      int s1 = __builtin_amdgcn_readfirstlane(s_src[k + 2]);
      int s2 = __builtin_amdgcn_readfirstlane(s_src[k + 4]);
      int s3 = __builtin_amdgcn_readfirstlane(s_src[k + 6]);
      float2 f0 = *(const float2*)(ftp + (size_t)s0 * 128);
      float2 f1 = *(const float2*)(ftp + (size_t)s1 * 128);
      float2 f2 = *(const float2*)(ftp + (size_t)s2 * 128);
      float2 f3 = *(const float2*)(ftp + (size_t)s3 * 128);
      float c0v = s_coef[ch][k][hh], c1v = s_coef[ch][k + 2][hh];
      float c2v = s_coef[ch][k + 4][hh], c3v = s_coef[ch][k + 6][hh];
      acc0 = fmaf(c0v, f0.x, acc0); acc1 = fmaf(c0v, f0.y, acc1);
      acc0 = fmaf(c1v, f1.x, acc0); acc1 = fmaf(c1v, f1.y, acc1);
      acc0 = fmaf(c2v, f2.x, acc0); acc1 = fmaf(c2v, f2.y, acc1);
      acc0 = fmaf(c3v, f3.x, acc0); acc1 = fmaf(c3v, f3.y, acc1);
    }
    for (; k < cnt; k += 2) {
      int s0 = __builtin_amdgcn_readfirstlane(s_src[k]);
      float c0v = s_coef[ch][k][hh];
      float2 f0 = *(const float2*)(ftp + (size_t)s0 * 128);
      acc0 = fmaf(c0v, f0.x, acc0); acc1 = fmaf(c0v, f0.y, acc1);
    }
  }

  // ---- denominator: butterfly over se-bits (lane bits 1..5), then 2 waves ----
#pragma unroll
  for (int off = 2; off <= 32; off <<= 1) {
    lp0 += __shfl_xor(lp0, off);
    lp1 += __shfl_xor(lp1, off);
  }
  // even lanes now hold (head0, head1) wave-sums; odd lanes (head2, head3)
  __syncthreads();
  if (lane == 0) { s_l[ch][w2][0] = lp0; s_l[ch][w2][1] = lp1; }
  if (lane == 1) { s_l[ch][w2][2] = lp0; s_l[ch][w2][3] = lp1; }
  // publish odd-wave partial accs
  if (w2 == 1) { s_part[ch][lane * 2] = acc0; s_part[ch][lane * 2 + 1] = acc1; }
  __syncthreads();
  float l = s_l[ch][0][hh] + s_l[ch][1][hh];
  float rl = 1.f / fmaxf(l, 1e-9f);
  float v0 = 0.f, v1 = 0.f;
  if (w2 == 0) {
    float2 b2 = *(const float2*)(P.bias + lane * 2);
    v0 = fmaf(acc0 + s_part[ch][lane * 2], rl, b2.x);
    v1 = fmaf(acc1 + s_part[ch][lane * 2 + 1], rl, b2.y);
  }
  if (LAYER == 0) {
    if (w2 == 0) {
      *(float2*)(P.out + (size_t)node * 128 + lane * 2) =
          make_float2(fmaxf(v0, 0.f), fmaxf(v1, 0.f));
    }
  } else {
    __syncthreads();  // s_part rewrite hazard vs combine reads
    if (w2 == 0) { s_part[ch][lane * 2] = v0; s_part[ch][lane * 2 + 1] = v1; }
    __syncthreads();
    if (w2 == 0 && lane < 16) {
      int f = lane * 2;
      float o0 = 0.25f * (s_part[ch][f] + s_part[ch][32 + f] + s_part[ch][64 + f] +
                          s_part[ch][96 + f]);
      float o1 = 0.25f * (s_part[ch][f + 1] + s_part[ch][33 + f] + s_part[ch][65 + f] +
                          s_part[ch][97 + f]);
      *(float2*)(P.out + (size_t)node * 32 + f) = make_float2(o0, o1);
    }
  }
}

extern "C" void kernel_launch(void* const* d_in, const int* in_sizes, int n_in,
                              void* d_out, int out_size, void* d_ws, size_t ws_size,
                              hipStream_t stream) {
  const float* x_am = (const float*)d_in[0];
  const float* x_ph = (const float*)d_in[1];
  const float* exist = (const float*)d_in[2];
  const float* am_exist = (const float*)d_in[3];
  const int* src = (const int*)d_in[4];
  const int* dst = (const int*)d_in[5];
  const float* W0a = (const float*)d_in[6];
  const float* al0a = (const float*)d_in[7];
  const float* ar0a = (const float*)d_in[8];
  const float* b0a = (const float*)d_in[9];
  const float* W0p = (const float*)d_in[10];
  const float* al0p = (const float*)d_in[11];
  const float* ar0p = (const float*)d_in[12];
  const float* b0p = (const float*)d_in[13];
  const float* W1a = (const float*)d_in[14];
  const float* al1a = (const float*)d_in[15];
  const float* ar1a = (const float*)d_in[16];
  const float* b1a = (const float*)d_in[17];
  const float* W1p = (const float*)d_in[18];
  const float* al1p = (const float*)d_in[19];
  const float* ar1p = (const float*)d_in[20];
  const float* b1p = (const float*)d_in[21];

  int n = in_sizes[0] / 128;  // 50000
  int E = in_sizes[2];        // 800000
  int N_pad = (n + 255) & ~255;
  int nb = (n + 255) / 256;
  int NB_pad = (nb + 63) & ~63;

  size_t szN = (size_t)N_pad * 4;
  size_t szOffs = (size_t)(N_pad + 8) * 4;
  size_t szE16 = (size_t)E * 16;
  size_t szFt = (size_t)n * 128 * 4;
  size_t szEl = (size_t)N_pad * 4 * 4;

  auto rnd = [](size_t b) { return (b + 255) & ~(size_t)255; };
  size_t fixed = 3 * rnd(szN) + rnd((size_t)NB_pad * 4) + rnd(szOffs) + rnd(szE16) +
                 4 * rnd(szEl);
  bool dual = ws_size >= fixed + 4 * rnd(szFt);

  char* p = (char*)d_ws;
  auto take = [&](size_t b) { char* q = p; p += (b + 255) & ~(size_t)255; return q; };
  int* counts = (int*)take(szN);
  int* cursor = (int*)take(szN);
  int* incl = (int*)take(szN);
  int* bsum = (int*)take((size_t)NB_pad * 4);
  int* offs = (int*)take(szOffs);
  int4* edge16 = (int4*)take(szE16);
  float* el_am = (float*)take(szEl);
  float* el_ph = (float*)take(szEl);
  float* er_am = (float*)take(szEl);
  float* er_ph = (float*)take(szEl);
  float* ft_am = (float*)take(szFt);
  float* ft_ph = dual ? (float*)take(szFt) : ft_am;
  float* hb_am = (float*)take(szFt);
  float* hb_ph = dual ? (float*)take(szFt) : hb_am;

  float* out_am = (float*)d_out;
  float* out_ph = out_am + (size_t)n * 32;

  // ---- CSR build ----
  hipMemsetAsync(counts, 0, szN, stream);
  hist_kernel<<<(E + 255) / 256, 256, 0, stream>>>(dst, counts, E);
  scan1_kernel<<<nb, 256, 0, stream>>>(counts, incl, bsum, n);
  scan2_kernel<<<1, 256, 0, stream>>>(bsum, nb);
  scan3_kernel<<<nb, 256, 0, stream>>>(counts, incl, bsum, offs, n, E);
  hipMemcpyAsync(cursor, offs, szN, hipMemcpyDeviceToDevice, stream);
  fill_kernel<<<(E + 255) / 256, 256, 0, stream>>>(src, dst, exist, am_exist,
                                                   cursor, edge16, E);

  int gg = (n + 127) / 128;
  GemmP g0a{x_am, W0a, al0a, ar0a, ft_am, el_am, er_am};
  GemmP g0p{x_ph, W0p, al0p, ar0p, ft_ph, el_ph, er_ph};
  GemmP g1a{hb_am, W1a, al1a, ar1a, ft_am, el_am, er_am};
  GemmP g1p{hb_ph, W1p, al1p, ar1p, ft_ph, el_ph, er_ph};
  ChP c0a{ft_am, el_am, er_am, b0a, hb_am};
  ChP c0p{ft_ph, el_ph, er_ph, b0p, hb_ph};
  ChP c1a{ft_am, el_am, er_am, b1a, out_am};
  ChP c1p{ft_ph, el_ph, er_ph, b1p, out_ph};

  if (dual) {
    gemm_kernel<<<dim3(gg, 2), 256, 0, stream>>>(g0a, g0p, n);
    gather_kernel<0><<<n, 256, 0, stream>>>(c0a, c0p, offs, edge16, n);
    gemm_kernel<<<dim3(gg, 2), 256, 0, stream>>>(g1a, g1p, n);
    gather_kernel<1><<<n, 256, 0, stream>>>(c1a, c1p, offs, edge16, n);
  } else {
    // sequential fallback: both halves run the same channel (duplicate
    // identical writes, benign); buffers aliased above.
    gemm_kernel<<<dim3(gg, 2), 256, 0, stream>>>(g0a, g0a, n);
    gather_kernel<0><<<n, 256, 0, stream>>>(c0a, c0a, offs, edge16, n);
    gemm_kernel<<<dim3(gg, 2), 256, 0, stream>>>(g1a, g1a, n);
    gather_kernel<1><<<n, 256, 0, stream>>>(c1a, c1a, offs, edge16, n);
    gemm_kernel<<<dim3(gg, 2), 256, 0, stream>>>(g0p, g0p, n);
    gather_kernel<0><<<n, 256, 0, stream>>>(c0p, c0p, offs, edge16, n);
    gemm_kernel<<<dim3(gg, 2), 256, 0, stream>>>(g1p, g1p, n);
    gather_kernel<1><<<n, 256, 0, stream>>>(c1p, c1p, offs, edge16, n);
  }
}

// Round 6
// 622.108 us; speedup vs baseline: 1.1690x; 1.0098x over previous
//
#include <hip/hip_runtime.h>

// ---------------------------------------------------------------------------
// DUPLEX GAT, round 6.
//   - dst-CSR build once: hist + parallel scan + fill (packed int4 edge recs,
//     cursor preseeded from offsets).
//   - Per layer (both channels per dispatch):
//       GEMM: fp32 reg-tiled, 2-phase K staging (32KB LDS), fused el/er
//             epilogue, grid.y = channel.
//       gather: ONE WAVE PER (node, channel). No LDS, no barriers.
//               64 lanes x float2 cover the 128-feat row (512B/load);
//               every lane redundantly computes its head's exp(e) so the
//               softmax denominator needs no reduction at all; edge records
//               prefetched one 4-batch ahead; head-mean via shfl.
// ---------------------------------------------------------------------------

struct GemmP { const float *X, *W, *al, *ar; float *Y, *el, *er; };
struct ChP   { const float *ft, *el, *er, *bias; float *out; };

__global__ void hist_kernel(const int* __restrict__ dst, int* __restrict__ counts, int E) {
  int e = blockIdx.x * blockDim.x + threadIdx.x;
  if (e < E) atomicAdd(&counts[dst[e]], 1);
}

__global__ __launch_bounds__(256) void scan1_kernel(const int* __restrict__ counts,
                                                    int* __restrict__ incl,
                                                    int* __restrict__ bsum, int n) {
  __shared__ int lds[256];
  int i = blockIdx.x * 256 + threadIdx.x;
  int v = (i < n) ? counts[i] : 0;
  lds[threadIdx.x] = v;
  __syncthreads();
  for (int off = 1; off < 256; off <<= 1) {
    int t = (threadIdx.x >= off) ? lds[threadIdx.x - off] : 0;
    __syncthreads();
    lds[threadIdx.x] += t;
    __syncthreads();
  }
  if (i < n) incl[i] = lds[threadIdx.x];
  if (threadIdx.x == 255) bsum[blockIdx.x] = lds[255];
}

__global__ __launch_bounds__(256) void scan2_kernel(int* __restrict__ bsum, int nb) {
  __shared__ int lds[256];
  int carry = 0;
  for (int base = 0; base < nb; base += 256) {
    int i = base + threadIdx.x;
    int v = (i < nb) ? bsum[i] : 0;
    lds[threadIdx.x] = v;
    __syncthreads();
    for (int off = 1; off < 256; off <<= 1) {
      int t = (threadIdx.x >= off) ? lds[threadIdx.x - off] : 0;
      __syncthreads();
      lds[threadIdx.x] += t;
      __syncthreads();
    }
    if (i < nb) bsum[i] = carry + lds[threadIdx.x] - v;  // exclusive
    carry += lds[255];
    __syncthreads();
  }
}

__global__ void scan3_kernel(const int* __restrict__ counts, const int* __restrict__ incl,
                             const int* __restrict__ bsum_ex, int* __restrict__ offsets,
                             int n, int E) {
  int i = blockIdx.x * blockDim.x + threadIdx.x;
  if (i < n) offsets[i] = incl[i] - counts[i] + bsum_ex[i >> 8];
  if (i == 0) offsets[n] = E;
}

// cursor preseeded with offsets -> atomicAdd returns absolute position.
// Packed edge record: {src, w_am bits, w_ph bits, 0} -> one dwordx4 scatter.
__global__ void fill_kernel(const int* __restrict__ src, const int* __restrict__ dst,
                            const float* __restrict__ exist, const float* __restrict__ am_exist,
                            int* __restrict__ cursor, int4* __restrict__ edge16, int E) {
  int e = blockIdx.x * blockDim.x + threadIdx.x;
  if (e >= E) return;
  int pos = atomicAdd(&cursor[dst[e]], 1);
  edge16[pos] = make_int4(src[e], __float_as_int(am_exist[e]), __float_as_int(exist[e]), 0);
}

// Y = X @ W (n x 128 @ 128 x 128, fp32), 2-phase K staging, fused el/er epilogue.
__global__ __launch_bounds__(256) void gemm_kernel(GemmP p0, GemmP p1, int n) {
  GemmP p = blockIdx.y ? p1 : p0;
  __shared__ float xs[64][128];  // xs[k][r], one 64-wide K phase
  int row0 = blockIdx.x << 7;
  int t = threadIdx.x;
  int tx = t & 15;  // cols tx*8..+7 (one head per thread)
  int ty = t >> 4;  // rows ty*8..+7
  const float4* W4 = (const float4*)p.W;
  float acc[8][8];
#pragma unroll
  for (int r = 0; r < 8; ++r)
#pragma unroll
    for (int c = 0; c < 8; ++c) acc[r][c] = 0.f;

  int r_st = t & 127;  // staging/epilogue row
  int row_st = row0 + r_st;
  bool ok = row_st < n;
#pragma unroll
  for (int ph = 0; ph < 2; ++ph) {
    __syncthreads();
#pragma unroll
    for (int i = 0; i < 8; ++i) {
      int idx = t + (i << 8);
      int r = idx & 127;
      int k4 = idx >> 7;  // 0..15
      float4 v = make_float4(0.f, 0.f, 0.f, 0.f);
      if (row0 + r < n)
        v = *(const float4*)(p.X + (size_t)(row0 + r) * 128 + (ph << 6) + (k4 << 2));
      xs[(k4 << 2) + 0][r] = v.x;
      xs[(k4 << 2) + 1][r] = v.y;
      xs[(k4 << 2) + 2][r] = v.z;
      xs[(k4 << 2) + 3][r] = v.w;
    }
    __syncthreads();
#pragma unroll 4
    for (int k = 0; k < 64; ++k) {
      int kg = (ph << 6) + k;
      float4 w0 = W4[(kg << 5) + (tx << 1)];
      float4 w1 = W4[(kg << 5) + (tx << 1) + 1];
      float4 x0 = *(const float4*)&xs[k][(ty << 3)];
      float4 x1 = *(const float4*)&xs[k][(ty << 3) + 4];
      float xv[8] = {x0.x, x0.y, x0.z, x0.w, x1.x, x1.y, x1.z, x1.w};
      float wv[8] = {w0.x, w0.y, w0.z, w0.w, w1.x, w1.y, w1.z, w1.w};
#pragma unroll
      for (int r = 0; r < 8; ++r)
#pragma unroll
        for (int c = 0; c < 8; ++c) acc[r][c] = fmaf(xv[r], wv[c], acc[r][c]);
    }
  }
#pragma unroll
  for (int r = 0; r < 8; ++r) {
    int row = row0 + (ty << 3) + r;
    if (row < n) {
      float4* yp = (float4*)(p.Y + (size_t)row * 128 + (tx << 3));
      yp[0] = make_float4(acc[r][0], acc[r][1], acc[r][2], acc[r][3]);
      yp[1] = make_float4(acc[r][4], acc[r][5], acc[r][6], acc[r][7]);
    }
  }
  // ---- fused el/er epilogue ----
  float al_v[8], ar_v[8];
  {
    const float4* al4 = (const float4*)p.al;
    const float4* ar4 = (const float4*)p.ar;
    float4 a0 = al4[tx * 2], a1 = al4[tx * 2 + 1];
    float4 r0 = ar4[tx * 2], r1 = ar4[tx * 2 + 1];
    al_v[0] = a0.x; al_v[1] = a0.y; al_v[2] = a0.z; al_v[3] = a0.w;
    al_v[4] = a1.x; al_v[5] = a1.y; al_v[6] = a1.z; al_v[7] = a1.w;
    ar_v[0] = r0.x; ar_v[1] = r0.y; ar_v[2] = r0.z; ar_v[3] = r0.w;
    ar_v[4] = r1.x; ar_v[5] = r1.y; ar_v[6] = r1.z; ar_v[7] = r1.w;
  }
  __syncthreads();  // reuse xs as reduction scratch (17.4KB <= 32KB)
  float* redl = &xs[0][0];        // [128][17]
  float* redr = redl + 128 * 17;  // [128][17]
#pragma unroll
  for (int r = 0; r < 8; ++r) {
    float pl = 0.f, pr = 0.f;
#pragma unroll
    for (int c = 0; c < 8; ++c) {
      pl = fmaf(acc[r][c], al_v[c], pl);
      pr = fmaf(acc[r][c], ar_v[c], pr);
    }
    redl[((ty << 3) + r) * 17 + tx] = pl;
    redr[((ty << 3) + r) * 17 + tx] = pr;
  }
  __syncthreads();
  if (t < 128 && ok) {
    float s[4], q[4];
#pragma unroll
    for (int h = 0; h < 4; ++h) {
      int b = r_st * 17 + h * 4;
      s[h] = redl[b] + redl[b + 1] + redl[b + 2] + redl[b + 3];
      q[h] = redr[b] + redr[b + 1] + redr[b + 2] + redr[b + 3];
    }
    *(float4*)(p.el + (size_t)row_st * 4) = make_float4(s[0], s[1], s[2], s[3]);
    *(float4*)(p.er + (size_t)row_st * 4) = make_float4(q[0], q[1], q[2], q[3]);
  }
}

// One wave per (node, channel). Block = 4 waves = 2 nodes x 2 channels.
// Lane i holds features 2i, 2i+1 (head hh = i>>4). Every lane accumulates its
// head's denominator redundantly -> no reduction needed. No LDS, no barriers.
template <int LAYER>
__global__ __launch_bounds__(256) void gather_kernel(ChP c0, ChP c1,
                                                     const int* __restrict__ offs,
                                                     const int4* __restrict__ edge16, int n) {
  int t = threadIdx.x;
  int w = t >> 6;
  int lane = t & 63;
  int node = blockIdx.x * 2 + (w >> 1);
  int ch = w & 1;
  if (node >= n) return;  // wave-uniform
  ChP P = ch ? c1 : c0;
  int hh = lane >> 4;

  int start = __builtin_amdgcn_readfirstlane(offs[node]);
  int end = __builtin_amdgcn_readfirstlane(offs[node + 1]);
  float er_h = P.er[(size_t)node * 4 + hh];
  const float* ftp = P.ft + lane * 2;
  const float* elp = P.el + hh;

  float acc0 = 0.f, acc1 = 0.f, l = 0.f;
  int k = start;
  int4 ed0, ed1, ed2, ed3;
  if (k + 4 <= end) {
    ed0 = edge16[k]; ed1 = edge16[k + 1]; ed2 = edge16[k + 2]; ed3 = edge16[k + 3];
  }
  while (k + 4 <= end) {
    int kn = k + 4;
    int4 nd0, nd1, nd2, nd3;
    if (kn + 4 <= end) {  // prefetch next batch's records
      nd0 = edge16[kn]; nd1 = edge16[kn + 1]; nd2 = edge16[kn + 2]; nd3 = edge16[kn + 3];
    }
    float el0 = elp[(size_t)ed0.x * 4];
    float el1 = elp[(size_t)ed1.x * 4];
    float el2 = elp[(size_t)ed2.x * 4];
    float el3 = elp[(size_t)ed3.x * 4];
    float2 f0 = *(const float2*)(ftp + (size_t)ed0.x * 128);
    float2 f1 = *(const float2*)(ftp + (size_t)ed1.x * 128);
    float2 f2 = *(const float2*)(ftp + (size_t)ed2.x * 128);
    float2 f3 = *(const float2*)(ftp + (size_t)ed3.x * 128);
    float w0 = __int_as_float(ch ? ed0.z : ed0.y);
    float w1 = __int_as_float(ch ? ed1.z : ed1.y);
    float w2 = __int_as_float(ch ? ed2.z : ed2.y);
    float w3 = __int_as_float(ch ? ed3.z : ed3.y);
    float e0 = el0 + er_h; e0 = (e0 > 0.f) ? e0 : 0.2f * e0;
    float e1 = el1 + er_h; e1 = (e1 > 0.f) ? e1 : 0.2f * e1;
    float e2 = el2 + er_h; e2 = (e2 > 0.f) ? e2 : 0.2f * e2;
    float e3 = el3 + er_h; e3 = (e3 > 0.f) ? e3 : 0.2f * e3;
    float x0 = __expf(e0), x1 = __expf(e1), x2 = __expf(e2), x3 = __expf(e3);
    l += x0 + x1 + x2 + x3;
    float c0v = x0 * w0, c1v = x1 * w1, c2v = x2 * w2, c3v = x3 * w3;
    acc0 = fmaf(c0v, f0.x, acc0); acc1 = fmaf(c0v, f0.y, acc1);
    acc0 = fmaf(c1v, f1.x, acc0); acc1 = fmaf(c1v, f1.y, acc1);
    acc0 = fmaf(c2v, f2.x, acc0); acc1 = fmaf(c2v, f2.y, acc1);
    acc0 = fmaf(c3v, f3.x, acc0); acc1 = fmaf(c3v, f3.y, acc1);
    ed0 = nd0; ed1 = nd1; ed2 = nd2; ed3 = nd3;
    k = kn;
  }
  for (; k < end; ++k) {
    int4 ed = edge16[k];
    float el0 = elp[(size_t)ed.x * 4];
    float2 f0 = *(const float2*)(ftp + (size_t)ed.x * 128);
    float w0 = __int_as_float(ch ? ed.z : ed.y);
    float e0 = el0 + er_h; e0 = (e0 > 0.f) ? e0 : 0.2f * e0;
    float x0 = __expf(e0);
    l += x0;
    float c0v = x0 * w0;
    acc0 = fmaf(c0v, f0.x, acc0); acc1 = fmaf(c0v, f0.y, acc1);
  }

  float rl = 1.f / fmaxf(l, 1e-9f);
  float2 b2 = *(const float2*)(P.bias + lane * 2);
  float v0 = fmaf(acc0, rl, b2.x);
  float v1 = fmaf(acc1, rl, b2.y);
  if (LAYER == 0) {
    *(float2*)(P.out + (size_t)node * 128 + lane * 2) =
        make_float2(fmaxf(v0, 0.f), fmaxf(v1, 0.f));
  } else {
    // mean over 4 heads: lanes L, L^16, L^32, L^48 hold the same in-head
    // feature pair for different heads
    v0 += __shfl_xor(v0, 16); v1 += __shfl_xor(v1, 16);
    v0 += __shfl_xor(v0, 32); v1 += __shfl_xor(v1, 32);
    if (lane < 16) {
      *(float2*)(P.out + (size_t)node * 32 + lane * 2) =
          make_float2(0.25f * v0, 0.25f * v1);
    }
  }
}

extern "C" void kernel_launch(void* const* d_in, const int* in_sizes, int n_in,
                              void* d_out, int out_size, void* d_ws, size_t ws_size,
                              hipStream_t stream) {
  const float* x_am = (const float*)d_in[0];
  const float* x_ph = (const float*)d_in[1];
  const float* exist = (const float*)d_in[2];
  const float* am_exist = (const float*)d_in[3];
  const int* src = (const int*)d_in[4];
  const int* dst = (const int*)d_in[5];
  const float* W0a = (const float*)d_in[6];
  const float* al0a = (const float*)d_in[7];
  const float* ar0a = (const float*)d_in[8];
  const float* b0a = (const float*)d_in[9];
  const float* W0p = (const float*)d_in[10];
  const float* al0p = (const float*)d_in[11];
  const float* ar0p = (const float*)d_in[12];
  const float* b0p = (const float*)d_in[13];
  const float* W1a = (const float*)d_in[14];
  const float* al1a = (const float*)d_in[15];
  const float* ar1a = (const float*)d_in[16];
  const float* b1a = (const float*)d_in[17];
  const float* W1p = (const float*)d_in[18];
  const float* al1p = (const float*)d_in[19];
  const float* ar1p = (const float*)d_in[20];
  const float* b1p = (const float*)d_in[21];

  int n = in_sizes[0] / 128;  // 50000
  int E = in_sizes[2];        // 800000
  int N_pad = (n + 255) & ~255;
  int nb = (n + 255) / 256;
  int NB_pad = (nb + 63) & ~63;

  size_t szN = (size_t)N_pad * 4;
  size_t szOffs = (size_t)(N_pad + 8) * 4;
  size_t szE16 = (size_t)E * 16;
  size_t szFt = (size_t)n * 128 * 4;
  size_t szEl = (size_t)N_pad * 4 * 4;

  auto rnd = [](size_t b) { return (b + 255) & ~(size_t)255; };
  size_t fixed = 3 * rnd(szN) + rnd((size_t)NB_pad * 4) + rnd(szOffs) + rnd(szE16) +
                 4 * rnd(szEl);
  bool dual = ws_size >= fixed + 4 * rnd(szFt);

  char* p = (char*)d_ws;
  auto take = [&](size_t b) { char* q = p; p += (b + 255) & ~(size_t)255; return q; };
  int* counts = (int*)take(szN);
  int* cursor = (int*)take(szN);
  int* incl = (int*)take(szN);
  int* bsum = (int*)take((size_t)NB_pad * 4);
  int* offs = (int*)take(szOffs);
  int4* edge16 = (int4*)take(szE16);
  float* el_am = (float*)take(szEl);
  float* el_ph = (float*)take(szEl);
  float* er_am = (float*)take(szEl);
  float* er_ph = (float*)take(szEl);
  float* ft_am = (float*)take(szFt);
  float* ft_ph = dual ? (float*)take(szFt) : ft_am;
  float* hb_am = (float*)take(szFt);
  float* hb_ph = dual ? (float*)take(szFt) : hb_am;

  float* out_am = (float*)d_out;
  float* out_ph = out_am + (size_t)n * 32;

  // ---- CSR build ----
  hipMemsetAsync(counts, 0, szN, stream);
  hist_kernel<<<(E + 255) / 256, 256, 0, stream>>>(dst, counts, E);
  scan1_kernel<<<nb, 256, 0, stream>>>(counts, incl, bsum, n);
  scan2_kernel<<<1, 256, 0, stream>>>(bsum, nb);
  scan3_kernel<<<nb, 256, 0, stream>>>(counts, incl, bsum, offs, n, E);
  hipMemcpyAsync(cursor, offs, szN, hipMemcpyDeviceToDevice, stream);
  fill_kernel<<<(E + 255) / 256, 256, 0, stream>>>(src, dst, exist, am_exist,
                                                   cursor, edge16, E);

  int gg = (n + 127) / 128;
  int gw = (n + 1) / 2;  // gather grid: 2 nodes x 2 channels per block
  GemmP g0a{x_am, W0a, al0a, ar0a, ft_am, el_am, er_am};
  GemmP g0p{x_ph, W0p, al0p, ar0p, ft_ph, el_ph, er_ph};
  GemmP g1a{hb_am, W1a, al1a, ar1a, ft_am, el_am, er_am};
  GemmP g1p{hb_ph, W1p, al1p, ar1p, ft_ph, el_ph, er_ph};
  ChP c0a{ft_am, el_am, er_am, b0a, hb_am};
  ChP c0p{ft_ph, el_ph, er_ph, b0p, hb_ph};
  ChP c1a{ft_am, el_am, er_am, b1a, out_am};
  ChP c1p{ft_ph, el_ph, er_ph, b1p, out_ph};

  if (dual) {
    gemm_kernel<<<dim3(gg, 2), 256, 0, stream>>>(g0a, g0p, n);
    gather_kernel<0><<<gw, 256, 0, stream>>>(c0a, c0p, offs, edge16, n);
    gemm_kernel<<<dim3(gg, 2), 256, 0, stream>>>(g1a, g1p, n);
    gather_kernel<1><<<gw, 256, 0, stream>>>(c1a, c1p, offs, edge16, n);
  } else {
    // sequential fallback: both halves run the same channel (duplicate
    // identical writes, benign); buffers aliased above.
    gemm_kernel<<<dim3(gg, 2), 256, 0, stream>>>(g0a, g0a, n);
    gather_kernel<0><<<gw, 256, 0, stream>>>(c0a, c0a, offs, edge16, n);
    gemm_kernel<<<dim3(gg, 2), 256, 0, stream>>>(g1a, g1a, n);
    gather_kernel<1><<<gw, 256, 0, stream>>>(c1a, c1a, offs, edge16, n);
    gemm_kernel<<<dim3(gg, 2), 256, 0, stream>>>(g0p, g0p, n);
    gather_kernel<0><<<gw, 256, 0, stream>>>(c0p, c0p, offs, edge16, n);
    gemm_kernel<<<dim3(gg, 2), 256, 0, stream>>>(g1p, g1p, n);
    gather_kernel<1><<<gw, 256, 0, stream>>>(c1p, c1p, offs, edge16, n);
  }
}

// Round 7
// 562.790 us; speedup vs baseline: 1.2922x; 1.1054x over previous
//
#include <hip/hip_runtime.h>
#include <hip/hip_fp16.h>

// ---------------------------------------------------------------------------
// DUPLEX GAT, round 7.
//   - dst-CSR build once: hist + parallel scan + fill (packed int4 edge recs,
//     cursor preseeded from offsets).
//   - Per layer (both channels per dispatch):
//       GEMM: fp32 reg-tiled, 2-phase K staging (32KB LDS), fused el/er
//             epilogue (fp32), ft output stored as FP16 (halves gather bytes).
//       gather: one wave per (node, channel), no LDS/barriers; lane i holds
//               features 2i,2i+1 as one __half2 load (4B); redundant per-lane
//               denominator (no reduction); edge records prefetched.
//   ft is fp16 ONLY on the gather path; el/er and hbuf (GEMM-1 input) stay
//   fp32, so GEMM dot-products never see fp16 inputs.
// ---------------------------------------------------------------------------

struct GemmP { const float *X, *W, *al, *ar; __half *Y; float *el, *er; };
struct ChP   { const __half *ft; const float *el, *er, *bias; float *out; };

__global__ void hist_kernel(const int* __restrict__ dst, int* __restrict__ counts, int E) {
  int e = blockIdx.x * blockDim.x + threadIdx.x;
  if (e < E) atomicAdd(&counts[dst[e]], 1);
}

__global__ __launch_bounds__(256) void scan1_kernel(const int* __restrict__ counts,
                                                    int* __restrict__ incl,
                                                    int* __restrict__ bsum, int n) {
  __shared__ int lds[256];
  int i = blockIdx.x * 256 + threadIdx.x;
  int v = (i < n) ? counts[i] : 0;
  lds[threadIdx.x] = v;
  __syncthreads();
  for (int off = 1; off < 256; off <<= 1) {
    int t = (threadIdx.x >= off) ? lds[threadIdx.x - off] : 0;
    __syncthreads();
    lds[threadIdx.x] += t;
    __syncthreads();
  }
  if (i < n) incl[i] = lds[threadIdx.x];
  if (threadIdx.x == 255) bsum[blockIdx.x] = lds[255];
}

__global__ __launch_bounds__(256) void scan2_kernel(int* __restrict__ bsum, int nb) {
  __shared__ int lds[256];
  int carry = 0;
  for (int base = 0; base < nb; base += 256) {
    int i = base + threadIdx.x;
    int v = (i < nb) ? bsum[i] : 0;
    lds[threadIdx.x] = v;
    __syncthreads();
    for (int off = 1; off < 256; off <<= 1) {
      int t = (threadIdx.x >= off) ? lds[threadIdx.x - off] : 0;
      __syncthreads();
      lds[threadIdx.x] += t;
      __syncthreads();
    }
    if (i < nb) bsum[i] = carry + lds[threadIdx.x] - v;  // exclusive
    carry += lds[255];
    __syncthreads();
  }
}

__global__ void scan3_kernel(const int* __restrict__ counts, const int* __restrict__ incl,
                             const int* __restrict__ bsum_ex, int* __restrict__ offsets,
                             int n, int E) {
  int i = blockIdx.x * blockDim.x + threadIdx.x;
  if (i < n) offsets[i] = incl[i] - counts[i] + bsum_ex[i >> 8];
  if (i == 0) offsets[n] = E;
}

// cursor preseeded with offsets -> atomicAdd returns absolute position.
__global__ void fill_kernel(const int* __restrict__ src, const int* __restrict__ dst,
                            const float* __restrict__ exist, const float* __restrict__ am_exist,
                            int* __restrict__ cursor, int4* __restrict__ edge16, int E) {
  int e = blockIdx.x * blockDim.x + threadIdx.x;
  if (e >= E) return;
  int pos = atomicAdd(&cursor[dst[e]], 1);
  edge16[pos] = make_int4(src[e], __float_as_int(am_exist[e]), __float_as_int(exist[e]), 0);
}

// Y = X @ W (n x 128 @ 128 x 128, fp32 compute), 2-phase K staging.
// Stores Y as fp16; fused fp32 el/er epilogue.
__global__ __launch_bounds__(256) void gemm_kernel(GemmP p0, GemmP p1, int n) {
  GemmP p = blockIdx.y ? p1 : p0;
  __shared__ float xs[64][128];  // xs[k][r], one 64-wide K phase
  int row0 = blockIdx.x << 7;
  int t = threadIdx.x;
  int tx = t & 15;  // cols tx*8..+7 (one head per thread)
  int ty = t >> 4;  // rows ty*8..+7
  const float4* W4 = (const float4*)p.W;
  float acc[8][8];
#pragma unroll
  for (int r = 0; r < 8; ++r)
#pragma unroll
    for (int c = 0; c < 8; ++c) acc[r][c] = 0.f;

  int r_st = t & 127;  // staging/epilogue row
  int row_st = row0 + r_st;
  bool ok = row_st < n;
#pragma unroll
  for (int ph = 0; ph < 2; ++ph) {
    __syncthreads();
#pragma unroll
    for (int i = 0; i < 8; ++i) {
      int idx = t + (i << 8);
      int r = idx & 127;
      int k4 = idx >> 7;  // 0..15
      float4 v = make_float4(0.f, 0.f, 0.f, 0.f);
      if (row0 + r < n)
        v = *(const float4*)(p.X + (size_t)(row0 + r) * 128 + (ph << 6) + (k4 << 2));
      xs[(k4 << 2) + 0][r] = v.x;
      xs[(k4 << 2) + 1][r] = v.y;
      xs[(k4 << 2) + 2][r] = v.z;
      xs[(k4 << 2) + 3][r] = v.w;
    }
    __syncthreads();
#pragma unroll 4
    for (int k = 0; k < 64; ++k) {
      int kg = (ph << 6) + k;
      float4 w0 = W4[(kg << 5) + (tx << 1)];
      float4 w1 = W4[(kg << 5) + (tx << 1) + 1];
      float4 x0 = *(const float4*)&xs[k][(ty << 3)];
      float4 x1 = *(const float4*)&xs[k][(ty << 3) + 4];
      float xv[8] = {x0.x, x0.y, x0.z, x0.w, x1.x, x1.y, x1.z, x1.w};
      float wv[8] = {w0.x, w0.y, w0.z, w0.w, w1.x, w1.y, w1.z, w1.w};
#pragma unroll
      for (int r = 0; r < 8; ++r)
#pragma unroll
        for (int c = 0; c < 8; ++c) acc[r][c] = fmaf(xv[r], wv[c], acc[r][c]);
    }
  }
#pragma unroll
  for (int r = 0; r < 8; ++r) {
    int row = row0 + (ty << 3) + r;
    if (row < n) {
      union { __half h[8]; uint4 u; } pk;
#pragma unroll
      for (int c = 0; c < 8; ++c) pk.h[c] = __float2half_rn(acc[r][c]);
      *(uint4*)(p.Y + (size_t)row * 128 + (tx << 3)) = pk.u;
    }
  }
  // ---- fused el/er epilogue (fp32) ----
  float al_v[8], ar_v[8];
  {
    const float4* al4 = (const float4*)p.al;
    const float4* ar4 = (const float4*)p.ar;
    float4 a0 = al4[tx * 2], a1 = al4[tx * 2 + 1];
    float4 r0 = ar4[tx * 2], r1 = ar4[tx * 2 + 1];
    al_v[0] = a0.x; al_v[1] = a0.y; al_v[2] = a0.z; al_v[3] = a0.w;
    al_v[4] = a1.x; al_v[5] = a1.y; al_v[6] = a1.z; al_v[7] = a1.w;
    ar_v[0] = r0.x; ar_v[1] = r0.y; ar_v[2] = r0.z; ar_v[3] = r0.w;
    ar_v[4] = r1.x; ar_v[5] = r1.y; ar_v[6] = r1.z; ar_v[7] = r1.w;
  }
  __syncthreads();  // reuse xs as reduction scratch (17.4KB <= 32KB)
  float* redl = &xs[0][0];        // [128][17]
  float* redr = redl + 128 * 17;  // [128][17]
#pragma unroll
  for (int r = 0; r < 8; ++r) {
    float pl = 0.f, pr = 0.f;
#pragma unroll
    for (int c = 0; c < 8; ++c) {
      pl = fmaf(acc[r][c], al_v[c], pl);
      pr = fmaf(acc[r][c], ar_v[c], pr);
    }
    redl[((ty << 3) + r) * 17 + tx] = pl;
    redr[((ty << 3) + r) * 17 + tx] = pr;
  }
  __syncthreads();
  if (t < 128 && ok) {
    float s[4], q[4];
#pragma unroll
    for (int h = 0; h < 4; ++h) {
      int b = r_st * 17 + h * 4;
      s[h] = redl[b] + redl[b + 1] + redl[b + 2] + redl[b + 3];
      q[h] = redr[b] + redr[b + 1] + redr[b + 2] + redr[b + 3];
    }
    *(float4*)(p.el + (size_t)row_st * 4) = make_float4(s[0], s[1], s[2], s[3]);
    *(float4*)(p.er + (size_t)row_st * 4) = make_float4(q[0], q[1], q[2], q[3]);
  }
}

// One wave per (node, channel). Block = 4 waves = 2 nodes x 2 channels.
// Lane i holds features 2i, 2i+1 (head hh = i>>4) as one __half2 load.
// Every lane accumulates its head's denominator redundantly -> no reduction.
template <int LAYER>
__global__ __launch_bounds__(256) void gather_kernel(ChP c0, ChP c1,
                                                     const int* __restrict__ offs,
                                                     const int4* __restrict__ edge16, int n) {
  int t = threadIdx.x;
  int w = t >> 6;
  int lane = t & 63;
  int node = blockIdx.x * 2 + (w >> 1);
  int ch = w & 1;
  if (node >= n) return;  // wave-uniform
  ChP P = ch ? c1 : c0;
  int hh = lane >> 4;

  int start = __builtin_amdgcn_readfirstlane(offs[node]);
  int end = __builtin_amdgcn_readfirstlane(offs[node + 1]);
  float er_h = P.er[(size_t)node * 4 + hh];
  const __half2* ftp = (const __half2*)P.ft + lane;  // + s*64 per row
  const float* elp = P.el + hh;

  float acc0 = 0.f, acc1 = 0.f, l = 0.f;
  int k = start;
  int4 ed0, ed1, ed2, ed3;
  if (k + 4 <= end) {
    ed0 = edge16[k]; ed1 = edge16[k + 1]; ed2 = edge16[k + 2]; ed3 = edge16[k + 3];
  }
  while (k + 4 <= end) {
    int kn = k + 4;
    int4 nd0, nd1, nd2, nd3;
    if (kn + 4 <= end) {  // prefetch next batch's records
      nd0 = edge16[kn]; nd1 = edge16[kn + 1]; nd2 = edge16[kn + 2]; nd3 = edge16[kn + 3];
    }
    float el0 = elp[(size_t)ed0.x * 4];
    float el1 = elp[(size_t)ed1.x * 4];
    float el2 = elp[(size_t)ed2.x * 4];
    float el3 = elp[(size_t)ed3.x * 4];
    float2 f0 = __half22float2(ftp[(size_t)ed0.x * 64]);
    float2 f1 = __half22float2(ftp[(size_t)ed1.x * 64]);
    float2 f2 = __half22float2(ftp[(size_t)ed2.x * 64]);
    float2 f3 = __half22float2(ftp[(size_t)ed3.x * 64]);
    float w0 = __int_as_float(ch ? ed0.z : ed0.y);
    float w1 = __int_as_float(ch ? ed1.z : ed1.y);
    float w2 = __int_as_float(ch ? ed2.z : ed2.y);
    float w3 = __int_as_float(ch ? ed3.z : ed3.y);
    float e0 = el0 + er_h; e0 = (e0 > 0.f) ? e0 : 0.2f * e0;
    float e1 = el1 + er_h; e1 = (e1 > 0.f) ? e1 : 0.2f * e1;
    float e2 = el2 + er_h; e2 = (e2 > 0.f) ? e2 : 0.2f * e2;
    float e3 = el3 + er_h; e3 = (e3 > 0.f) ? e3 : 0.2f * e3;
    float x0 = __expf(e0), x1 = __expf(e1), x2 = __expf(e2), x3 = __expf(e3);
    l += x0 + x1 + x2 + x3;
    float c0v = x0 * w0, c1v = x1 * w1, c2v = x2 * w2, c3v = x3 * w3;
    acc0 = fmaf(c0v, f0.x, acc0); acc1 = fmaf(c0v, f0.y, acc1);
    acc0 = fmaf(c1v, f1.x, acc0); acc1 = fmaf(c1v, f1.y, acc1);
    acc0 = fmaf(c2v, f2.x, acc0); acc1 = fmaf(c2v, f2.y, acc1);
    acc0 = fmaf(c3v, f3.x, acc0); acc1 = fmaf(c3v, f3.y, acc1);
    ed0 = nd0; ed1 = nd1; ed2 = nd2; ed3 = nd3;
    k = kn;
  }
  for (; k < end; ++k) {
    int4 ed = edge16[k];
    float el0 = elp[(size_t)ed.x * 4];
    float2 f0 = __half22float2(ftp[(size_t)ed.x * 64]);
    float w0 = __int_as_float(ch ? ed.z : ed.y);
    float e0 = el0 + er_h; e0 = (e0 > 0.f) ? e0 : 0.2f * e0;
    float x0 = __expf(e0);
    l += x0;
    float c0v = x0 * w0;
    acc0 = fmaf(c0v, f0.x, acc0); acc1 = fmaf(c0v, f0.y, acc1);
  }

  float rl = 1.f / fmaxf(l, 1e-9f);
  float2 b2 = *(const float2*)(P.bias + lane * 2);
  float v0 = fmaf(acc0, rl, b2.x);
  float v1 = fmaf(acc1, rl, b2.y);
  if (LAYER == 0) {
    *(float2*)(P.out + (size_t)node * 128 + lane * 2) =
        make_float2(fmaxf(v0, 0.f), fmaxf(v1, 0.f));
  } else {
    // mean over 4 heads: lanes L, L^16, L^32, L^48 hold the same in-head
    // feature pair for different heads
    v0 += __shfl_xor(v0, 16); v1 += __shfl_xor(v1, 16);
    v0 += __shfl_xor(v0, 32); v1 += __shfl_xor(v1, 32);
    if (lane < 16) {
      *(float2*)(P.out + (size_t)node * 32 + lane * 2) =
          make_float2(0.25f * v0, 0.25f * v1);
    }
  }
}

extern "C" void kernel_launch(void* const* d_in, const int* in_sizes, int n_in,
                              void* d_out, int out_size, void* d_ws, size_t ws_size,
                              hipStream_t stream) {
  const float* x_am = (const float*)d_in[0];
  const float* x_ph = (const float*)d_in[1];
  const float* exist = (const float*)d_in[2];
  const float* am_exist = (const float*)d_in[3];
  const int* src = (const int*)d_in[4];
  const int* dst = (const int*)d_in[5];
  const float* W0a = (const float*)d_in[6];
  const float* al0a = (const float*)d_in[7];
  const float* ar0a = (const float*)d_in[8];
  const float* b0a = (const float*)d_in[9];
  const float* W0p = (const float*)d_in[10];
  const float* al0p = (const float*)d_in[11];
  const float* ar0p = (const float*)d_in[12];
  const float* b0p = (const float*)d_in[13];
  const float* W1a = (const float*)d_in[14];
  const float* al1a = (const float*)d_in[15];
  const float* ar1a = (const float*)d_in[16];
  const float* b1a = (const float*)d_in[17];
  const float* W1p = (const float*)d_in[18];
  const float* al1p = (const float*)d_in[19];
  const float* ar1p = (const float*)d_in[20];
  const float* b1p = (const float*)d_in[21];

  int n = in_sizes[0] / 128;  // 50000
  int E = in_sizes[2];        // 800000
  int N_pad = (n + 255) & ~255;
  int nb = (n + 255) / 256;
  int NB_pad = (nb + 63) & ~63;

  size_t szN = (size_t)N_pad * 4;
  size_t szOffs = (size_t)(N_pad + 8) * 4;
  size_t szE16 = (size_t)E * 16;
  size_t szFt16 = (size_t)n * 128 * 2;  // fp16 ft
  size_t szHb = (size_t)n * 128 * 4;    // fp32 hidden buf
  size_t szEl = (size_t)N_pad * 4 * 4;

  auto rnd = [](size_t b) { return (b + 255) & ~(size_t)255; };
  size_t fixed = 3 * rnd(szN) + rnd((size_t)NB_pad * 4) + rnd(szOffs) + rnd(szE16) +
                 4 * rnd(szEl);
  bool dual = ws_size >= fixed + 2 * rnd(szFt16) + 2 * rnd(szHb);

  char* p = (char*)d_ws;
  auto take = [&](size_t b) { char* q = p; p += (b + 255) & ~(size_t)255; return q; };
  int* counts = (int*)take(szN);
  int* cursor = (int*)take(szN);
  int* incl = (int*)take(szN);
  int* bsum = (int*)take((size_t)NB_pad * 4);
  int* offs = (int*)take(szOffs);
  int4* edge16 = (int4*)take(szE16);
  float* el_am = (float*)take(szEl);
  float* el_ph = (float*)take(szEl);
  float* er_am = (float*)take(szEl);
  float* er_ph = (float*)take(szEl);
  __half* ft_am = (__half*)take(szFt16);
  __half* ft_ph = dual ? (__half*)take(szFt16) : ft_am;
  float* hb_am = (float*)take(szHb);
  float* hb_ph = dual ? (float*)take(szHb) : hb_am;

  float* out_am = (float*)d_out;
  float* out_ph = out_am + (size_t)n * 32;

  // ---- CSR build ----
  hipMemsetAsync(counts, 0, szN, stream);
  hist_kernel<<<(E + 255) / 256, 256, 0, stream>>>(dst, counts, E);
  scan1_kernel<<<nb, 256, 0, stream>>>(counts, incl, bsum, n);
  scan2_kernel<<<1, 256, 0, stream>>>(bsum, nb);
  scan3_kernel<<<nb, 256, 0, stream>>>(counts, incl, bsum, offs, n, E);
  hipMemcpyAsync(cursor, offs, szN, hipMemcpyDeviceToDevice, stream);
  fill_kernel<<<(E + 255) / 256, 256, 0, stream>>>(src, dst, exist, am_exist,
                                                   cursor, edge16, E);

  int gg = (n + 127) / 128;
  int gw = (n + 1) / 2;  // gather grid: 2 nodes x 2 channels per block
  GemmP g0a{x_am, W0a, al0a, ar0a, ft_am, el_am, er_am};
  GemmP g0p{x_ph, W0p, al0p, ar0p, ft_ph, el_ph, er_ph};
  GemmP g1a{hb_am, W1a, al1a, ar1a, ft_am, el_am, er_am};
  GemmP g1p{hb_ph, W1p, al1p, ar1p, ft_ph, el_ph, er_ph};
  ChP c0a{ft_am, el_am, er_am, b0a, hb_am};
  ChP c0p{ft_ph, el_ph, er_ph, b0p, hb_ph};
  ChP c1a{ft_am, el_am, er_am, b1a, out_am};
  ChP c1p{ft_ph, el_ph, er_ph, b1p, out_ph};

  if (dual) {
    gemm_kernel<<<dim3(gg, 2), 256, 0, stream>>>(g0a, g0p, n);
    gather_kernel<0><<<gw, 256, 0, stream>>>(c0a, c0p, offs, edge16, n);
    gemm_kernel<<<dim3(gg, 2), 256, 0, stream>>>(g1a, g1p, n);
    gather_kernel<1><<<gw, 256, 0, stream>>>(c1a, c1p, offs, edge16, n);
  } else {
    // sequential fallback: both halves run the same channel (duplicate
    // identical writes, benign); buffers aliased above.
    gemm_kernel<<<dim3(gg, 2), 256, 0, stream>>>(g0a, g0a, n);
    gather_kernel<0><<<gw, 256, 0, stream>>>(c0a, c0a, offs, edge16, n);
    gemm_kernel<<<dim3(gg, 2), 256, 0, stream>>>(g1a, g1a, n);
    gather_kernel<1><<<gw, 256, 0, stream>>>(c1a, c1a, offs, edge16, n);
    gemm_kernel<<<dim3(gg, 2), 256, 0, stream>>>(g0p, g0p, n);
    gather_kernel<0><<<gw, 256, 0, stream>>>(c0p, c0p, offs, edge16, n);
    gemm_kernel<<<dim3(gg, 2), 256, 0, stream>>>(g1p, g1p, n);
    gather_kernel<1><<<gw, 256, 0, stream>>>(c1p, c1p, offs, edge16, n);
  }
}

// Round 8
// 434.839 us; speedup vs baseline: 1.6725x; 1.2942x over previous
//
#include <hip/hip_runtime.h>
#include <hip/hip_fp16.h>

// ---------------------------------------------------------------------------
// DUPLEX GAT, round 8.
//   - dst-CSR build once (hist + parallel scan + fill; packed int4 edge recs).
//   - W prep: convert+transpose all 4 weight mats to fp16 Wt[n][k] (one tiny
//     kernel; makes MFMA B-fragments contiguous 16B loads).
//   - Per layer (both channels per dispatch):
//       GEMM (MFMA): A fp32 -> fp16 inline, mfma_f32_16x16x32_f16, fp32 acc.
//         128x128 tile, 4 waves x (2 row-tiles x 8 col-tiles), K in two
//         64-wide LDS phases (36KB, stride 136h = conflict-free b128 frags).
//         Epilogue: acc -> LDS fp16 -> coalesced ft stores + per-row el/er
//         head-dots (no cross-lane reduction), el/er fp32 from fp32 acc.
//       gather: one wave per (node, channel), no LDS/barriers; __half2 ft
//         loads; redundant per-lane denominator; prefetched edge records.
// ---------------------------------------------------------------------------

typedef _Float16 f16x8 __attribute__((ext_vector_type(8)));
typedef float f32x4 __attribute__((ext_vector_type(4)));

struct GemmP { const float* X; const __half* Wt; const float *al, *ar; __half* Y; float *el, *er; };
struct ChP   { const __half* ft; const float *el, *er, *bias; float *out; };

__global__ void hist_kernel(const int* __restrict__ dst, int* __restrict__ counts, int E) {
  int e = blockIdx.x * blockDim.x + threadIdx.x;
  if (e < E) atomicAdd(&counts[dst[e]], 1);
}

__global__ __launch_bounds__(256) void scan1_kernel(const int* __restrict__ counts,
                                                    int* __restrict__ incl,
                                                    int* __restrict__ bsum, int n) {
  __shared__ int lds[256];
  int i = blockIdx.x * 256 + threadIdx.x;
  int v = (i < n) ? counts[i] : 0;
  lds[threadIdx.x] = v;
  __syncthreads();
  for (int off = 1; off < 256; off <<= 1) {
    int t = (threadIdx.x >= off) ? lds[threadIdx.x - off] : 0;
    __syncthreads();
    lds[threadIdx.x] += t;
    __syncthreads();
  }
  if (i < n) incl[i] = lds[threadIdx.x];
  if (threadIdx.x == 255) bsum[blockIdx.x] = lds[255];
}

__global__ __launch_bounds__(256) void scan2_kernel(int* __restrict__ bsum, int nb) {
  __shared__ int lds[256];
  int carry = 0;
  for (int base = 0; base < nb; base += 256) {
    int i = base + threadIdx.x;
    int v = (i < nb) ? bsum[i] : 0;
    lds[threadIdx.x] = v;
    __syncthreads();
    for (int off = 1; off < 256; off <<= 1) {
      int t = (threadIdx.x >= off) ? lds[threadIdx.x - off] : 0;
      __syncthreads();
      lds[threadIdx.x] += t;
      __syncthreads();
    }
    if (i < nb) bsum[i] = carry + lds[threadIdx.x] - v;  // exclusive
    carry += lds[255];
    __syncthreads();
  }
}

__global__ void scan3_kernel(const int* __restrict__ counts, const int* __restrict__ incl,
                             const int* __restrict__ bsum_ex, int* __restrict__ offsets,
                             int n, int E) {
  int i = blockIdx.x * blockDim.x + threadIdx.x;
  if (i < n) offsets[i] = incl[i] - counts[i] + bsum_ex[i >> 8];
  if (i == 0) offsets[n] = E;
}

__global__ void fill_kernel(const int* __restrict__ src, const int* __restrict__ dst,
                            const float* __restrict__ exist, const float* __restrict__ am_exist,
                            int* __restrict__ cursor, int4* __restrict__ edge16, int E) {
  int e = blockIdx.x * blockDim.x + threadIdx.x;
  if (e >= E) return;
  int pos = atomicAdd(&cursor[dst[e]], 1);
  edge16[pos] = make_int4(src[e], __float_as_int(am_exist[e]), __float_as_int(exist[e]), 0);
}

// Convert + transpose 4 weight matrices: Wt_m[nn][k] = (half)W_m[k][nn].
__global__ void wprep_kernel(const float* __restrict__ W0a, const float* __restrict__ W0p,
                             const float* __restrict__ W1a, const float* __restrict__ W1p,
                             __half* __restrict__ Wt) {
  int m = blockIdx.y;
  const float* W = (m == 0) ? W0a : (m == 1) ? W0p : (m == 2) ? W1a : W1p;
  __half* O = Wt + (size_t)m * 16384;
  int i = blockIdx.x * 256 + threadIdx.x;  // 0..16383
  int nn = i >> 7, k = i & 127;
  O[nn * 128 + k] = __float2half_rn(W[k * 128 + nn]);
}

// Y(fp16) = fp16(X) @ fp16(W), fp32 MFMA accumulate; fused fp32 el/er epilogue.
// Block: 256 thr = 4 waves; tile 128 rows x 128 cols; K=128 in two 64 phases.
__global__ __launch_bounds__(256) void gemm_kernel(GemmP p0, GemmP p1, int n) {
  GemmP p = blockIdx.y ? p1 : p0;
  constexpr int LDH = 72;   // staging stride (halves): 144B, 16B-aligned, conflict-free b128
  constexpr int LDE = 136;  // epilogue stride (halves): 272B
  __shared__ __half lds[2 * 128 * LDH];  // 36,864 B
  __half* As = lds;
  __half* Ws = lds + 128 * LDH;
  int t = threadIdx.x;
  int row0 = blockIdx.x << 7;
  int wv = t >> 6, lane = t & 63;
  int m = lane & 15, q = lane >> 4;

  f32x4 acc[2][8];
#pragma unroll
  for (int rt = 0; rt < 2; ++rt)
#pragma unroll
    for (int ct = 0; ct < 8; ++ct) acc[rt][ct] = (f32x4){0.f, 0.f, 0.f, 0.f};

#pragma unroll
  for (int kh = 0; kh < 2; ++kh) {
    __syncthreads();  // protect previous phase's fragment reads
    // stage A: 128 rows x 64 k, fp32 -> fp16
#pragma unroll
    for (int i = 0; i < 8; ++i) {
      int c = t + (i << 8);  // 0..2047 float4-chunks
      int r = c >> 4;
      int f4 = c & 15;
      float4 v = make_float4(0.f, 0.f, 0.f, 0.f);
      if (row0 + r < n)
        v = *(const float4*)(p.X + (size_t)(row0 + r) * 128 + (kh << 6) + (f4 << 2));
      union { __half h[4]; uint2 u; } pk;
      pk.h[0] = __float2half_rn(v.x); pk.h[1] = __float2half_rn(v.y);
      pk.h[2] = __float2half_rn(v.z); pk.h[3] = __float2half_rn(v.w);
      *(uint2*)(As + r * LDH + (f4 << 2)) = pk.u;
    }
    // stage Wt: 128 n-rows x 64 k (already fp16)
#pragma unroll
    for (int i = 0; i < 4; ++i) {
      int c = t + (i << 8);  // 0..1023 chunks of 8 halves
      int r = c >> 3;
      int o8 = c & 7;
      uint4 v = *(const uint4*)(p.Wt + (size_t)r * 128 + (kh << 6) + (o8 << 3));
      *(uint4*)(Ws + r * LDH + (o8 << 3)) = v;
    }
    __syncthreads();
#pragma unroll
    for (int kc = 0; kc < 2; ++kc) {
      f16x8 a0 = *(const f16x8*)(As + (wv * 32 + m) * LDH + kc * 32 + q * 8);
      f16x8 a1 = *(const f16x8*)(As + (wv * 32 + 16 + m) * LDH + kc * 32 + q * 8);
#pragma unroll
      for (int ct = 0; ct < 8; ++ct) {
        f16x8 b = *(const f16x8*)(Ws + (ct * 16 + m) * LDH + kc * 32 + q * 8);
        acc[0][ct] = __builtin_amdgcn_mfma_f32_16x16x32_f16(a0, b, acc[0][ct], 0, 0, 0);
        acc[1][ct] = __builtin_amdgcn_mfma_f32_16x16x32_f16(a1, b, acc[1][ct], 0, 0, 0);
      }
    }
  }
  // ---- epilogue: acc -> LDS fp16 (C/D layout: col=lane&15, row=quad*4+reg) ----
  __syncthreads();  // everyone done with As/Ws fragments
#pragma unroll
  for (int rt = 0; rt < 2; ++rt) {
    int rbase = wv * 32 + rt * 16 + q * 4;
#pragma unroll
    for (int ct = 0; ct < 8; ++ct) {
      int col = ct * 16 + m;
#pragma unroll
      for (int r = 0; r < 4; ++r)
        lds[(rbase + r) * LDE + col] = __float2half_rn(acc[rt][ct][r]);
    }
  }
  __syncthreads();
  // 2 threads per row: half = cols 0..63 / 64..127. ft store + el/er head-dots.
  {
    int r = t & 127;
    int half = t >> 7;
    int row = row0 + r;
    if (row < n) {
      float e0 = 0.f, e1 = 0.f, r0 = 0.f, r1 = 0.f;
#pragma unroll
      for (int i = 0; i < 8; ++i) {
        int cbase = half * 64 + i * 8;
        f16x8 v = *(const f16x8*)(lds + r * LDE + cbase);
        *(uint4*)(p.Y + (size_t)row * 128 + cbase) = *(const uint4*)&v;
#pragma unroll
        for (int j = 0; j < 8; ++j) {
          float f = (float)v[j];
          float av = p.al[cbase + j];
          float rv = p.ar[cbase + j];
          if (((i * 8 + j) >> 5) == 0) { e0 = fmaf(f, av, e0); r0 = fmaf(f, rv, r0); }
          else                         { e1 = fmaf(f, av, e1); r1 = fmaf(f, rv, r1); }
        }
      }
      *(float2*)(p.el + (size_t)row * 4 + half * 2) = make_float2(e0, e1);
      *(float2*)(p.er + (size_t)row * 4 + half * 2) = make_float2(r0, r1);
    }
  }
}

// One wave per (node, channel). Block = 4 waves = 2 nodes x 2 channels.
// Lane i holds features 2i, 2i+1 (head hh = i>>4) as one __half2 load.
// Every lane accumulates its head's denominator redundantly -> no reduction.
template <int LAYER>
__global__ __launch_bounds__(256) void gather_kernel(ChP c0, ChP c1,
                                                     const int* __restrict__ offs,
                                                     const int4* __restrict__ edge16, int n) {
  int t = threadIdx.x;
  int w = t >> 6;
  int lane = t & 63;
  int node = blockIdx.x * 2 + (w >> 1);
  int ch = w & 1;
  if (node >= n) return;  // wave-uniform
  ChP P = ch ? c1 : c0;
  int hh = lane >> 4;

  int start = __builtin_amdgcn_readfirstlane(offs[node]);
  int end = __builtin_amdgcn_readfirstlane(offs[node + 1]);
  float er_h = P.er[(size_t)node * 4 + hh];
  const __half2* ftp = (const __half2*)P.ft + lane;  // + s*64 per row
  const float* elp = P.el + hh;

  float acc0 = 0.f, acc1 = 0.f, l = 0.f;
  int k = start;
  int4 ed0, ed1, ed2, ed3;
  if (k + 4 <= end) {
    ed0 = edge16[k]; ed1 = edge16[k + 1]; ed2 = edge16[k + 2]; ed3 = edge16[k + 3];
  }
  while (k + 4 <= end) {
    int kn = k + 4;
    int4 nd0, nd1, nd2, nd3;
    if (kn + 4 <= end) {  // prefetch next batch's records
      nd0 = edge16[kn]; nd1 = edge16[kn + 1]; nd2 = edge16[kn + 2]; nd3 = edge16[kn + 3];
    }
    float el0 = elp[(size_t)ed0.x * 4];
    float el1 = elp[(size_t)ed1.x * 4];
    float el2 = elp[(size_t)ed2.x * 4];
    float el3 = elp[(size_t)ed3.x * 4];
    float2 f0 = __half22float2(ftp[(size_t)ed0.x * 64]);
    float2 f1 = __half22float2(ftp[(size_t)ed1.x * 64]);
    float2 f2 = __half22float2(ftp[(size_t)ed2.x * 64]);
    float2 f3 = __half22float2(ftp[(size_t)ed3.x * 64]);
    float w0 = __int_as_float(ch ? ed0.z : ed0.y);
    float w1 = __int_as_float(ch ? ed1.z : ed1.y);
    float w2 = __int_as_float(ch ? ed2.z : ed2.y);
    float w3 = __int_as_float(ch ? ed3.z : ed3.y);
    float e0 = el0 + er_h; e0 = (e0 > 0.f) ? e0 : 0.2f * e0;
    float e1 = el1 + er_h; e1 = (e1 > 0.f) ? e1 : 0.2f * e1;
    float e2 = el2 + er_h; e2 = (e2 > 0.f) ? e2 : 0.2f * e2;
    float e3 = el3 + er_h; e3 = (e3 > 0.f) ? e3 : 0.2f * e3;
    float x0 = __expf(e0), x1 = __expf(e1), x2 = __expf(e2), x3 = __expf(e3);
    l += x0 + x1 + x2 + x3;
    float c0v = x0 * w0, c1v = x1 * w1, c2v = x2 * w2, c3v = x3 * w3;
    acc0 = fmaf(c0v, f0.x, acc0); acc1 = fmaf(c0v, f0.y, acc1);
    acc0 = fmaf(c1v, f1.x, acc0); acc1 = fmaf(c1v, f1.y, acc1);
    acc0 = fmaf(c2v, f2.x, acc0); acc1 = fmaf(c2v, f2.y, acc1);
    acc0 = fmaf(c3v, f3.x, acc0); acc1 = fmaf(c3v, f3.y, acc1);
    ed0 = nd0; ed1 = nd1; ed2 = nd2; ed3 = nd3;
    k = kn;
  }
  for (; k < end; ++k) {
    int4 ed = edge16[k];
    float el0 = elp[(size_t)ed.x * 4];
    float2 f0 = __half22float2(ftp[(size_t)ed.x * 64]);
    float w0 = __int_as_float(ch ? ed.z : ed.y);
    float e0 = el0 + er_h; e0 = (e0 > 0.f) ? e0 : 0.2f * e0;
    float x0 = __expf(e0);
    l += x0;
    float c0v = x0 * w0;
    acc0 = fmaf(c0v, f0.x, acc0); acc1 = fmaf(c0v, f0.y, acc1);
  }

  float rl = 1.f / fmaxf(l, 1e-9f);
  float2 b2 = *(const float2*)(P.bias + lane * 2);
  float v0 = fmaf(acc0, rl, b2.x);
  float v1 = fmaf(acc1, rl, b2.y);
  if (LAYER == 0) {
    *(float2*)(P.out + (size_t)node * 128 + lane * 2) =
        make_float2(fmaxf(v0, 0.f), fmaxf(v1, 0.f));
  } else {
    v0 += __shfl_xor(v0, 16); v1 += __shfl_xor(v1, 16);
    v0 += __shfl_xor(v0, 32); v1 += __shfl_xor(v1, 32);
    if (lane < 16) {
      *(float2*)(P.out + (size_t)node * 32 + lane * 2) =
          make_float2(0.25f * v0, 0.25f * v1);
    }
  }
}

extern "C" void kernel_launch(void* const* d_in, const int* in_sizes, int n_in,
                              void* d_out, int out_size, void* d_ws, size_t ws_size,
                              hipStream_t stream) {
  const float* x_am = (const float*)d_in[0];
  const float* x_ph = (const float*)d_in[1];
  const float* exist = (const float*)d_in[2];
  const float* am_exist = (const float*)d_in[3];
  const int* src = (const int*)d_in[4];
  const int* dst = (const int*)d_in[5];
  const float* W0a = (const float*)d_in[6];
  const float* al0a = (const float*)d_in[7];
  const float* ar0a = (const float*)d_in[8];
  const float* b0a = (const float*)d_in[9];
  const float* W0p = (const float*)d_in[10];
  const float* al0p = (const float*)d_in[11];
  const float* ar0p = (const float*)d_in[12];
  const float* b0p = (const float*)d_in[13];
  const float* W1a = (const float*)d_in[14];
  const float* al1a = (const float*)d_in[15];
  const float* ar1a = (const float*)d_in[16];
  const float* b1a = (const float*)d_in[17];
  const float* W1p = (const float*)d_in[18];
  const float* al1p = (const float*)d_in[19];
  const float* ar1p = (const float*)d_in[20];
  const float* b1p = (const float*)d_in[21];

  int n = in_sizes[0] / 128;  // 50000
  int E = in_sizes[2];        // 800000
  int N_pad = (n + 255) & ~255;
  int nb = (n + 255) / 256;
  int NB_pad = (nb + 63) & ~63;

  size_t szN = (size_t)N_pad * 4;
  size_t szOffs = (size_t)(N_pad + 8) * 4;
  size_t szE16 = (size_t)E * 16;
  size_t szFt16 = (size_t)n * 128 * 2;  // fp16 ft
  size_t szHb = (size_t)n * 128 * 4;    // fp32 hidden buf
  size_t szEl = (size_t)N_pad * 4 * 4;
  size_t szWt = (size_t)4 * 128 * 128 * 2;  // 4 transposed fp16 weight mats

  auto rnd = [](size_t b) { return (b + 255) & ~(size_t)255; };
  size_t fixed = 3 * rnd(szN) + rnd((size_t)NB_pad * 4) + rnd(szOffs) + rnd(szE16) +
                 4 * rnd(szEl) + rnd(szWt);
  bool dual = ws_size >= fixed + 2 * rnd(szFt16) + 2 * rnd(szHb);

  char* p = (char*)d_ws;
  auto take = [&](size_t b) { char* q = p; p += (b + 255) & ~(size_t)255; return q; };
  int* counts = (int*)take(szN);
  int* cursor = (int*)take(szN);
  int* incl = (int*)take(szN);
  int* bsum = (int*)take((size_t)NB_pad * 4);
  int* offs = (int*)take(szOffs);
  int4* edge16 = (int4*)take(szE16);
  __half* Wt = (__half*)take(szWt);
  float* el_am = (float*)take(szEl);
  float* el_ph = (float*)take(szEl);
  float* er_am = (float*)take(szEl);
  float* er_ph = (float*)take(szEl);
  __half* ft_am = (__half*)take(szFt16);
  __half* ft_ph = dual ? (__half*)take(szFt16) : ft_am;
  float* hb_am = (float*)take(szHb);
  float* hb_ph = dual ? (float*)take(szHb) : hb_am;

  float* out_am = (float*)d_out;
  float* out_ph = out_am + (size_t)n * 32;

  // ---- CSR build + weight prep ----
  hipMemsetAsync(counts, 0, szN, stream);
  hist_kernel<<<(E + 255) / 256, 256, 0, stream>>>(dst, counts, E);
  wprep_kernel<<<dim3(64, 4), 256, 0, stream>>>(W0a, W0p, W1a, W1p, Wt);
  scan1_kernel<<<nb, 256, 0, stream>>>(counts, incl, bsum, n);
  scan2_kernel<<<1, 256, 0, stream>>>(bsum, nb);
  scan3_kernel<<<nb, 256, 0, stream>>>(counts, incl, bsum, offs, n, E);
  hipMemcpyAsync(cursor, offs, szN, hipMemcpyDeviceToDevice, stream);
  fill_kernel<<<(E + 255) / 256, 256, 0, stream>>>(src, dst, exist, am_exist,
                                                   cursor, edge16, E);

  int gg = (n + 127) / 128;
  int gw = (n + 1) / 2;
  GemmP g0a{x_am, Wt,          al0a, ar0a, ft_am, el_am, er_am};
  GemmP g0p{x_ph, Wt + 16384,  al0p, ar0p, ft_ph, el_ph, er_ph};
  GemmP g1a{hb_am, Wt + 32768, al1a, ar1a, ft_am, el_am, er_am};
  GemmP g1p{hb_ph, Wt + 49152, al1p, ar1p, ft_ph, el_ph, er_ph};
  ChP c0a{ft_am, el_am, er_am, b0a, hb_am};
  ChP c0p{ft_ph, el_ph, er_ph, b0p, hb_ph};
  ChP c1a{ft_am, el_am, er_am, b1a, out_am};
  ChP c1p{ft_ph, el_ph, er_ph, b1p, out_ph};

  if (dual) {
    gemm_kernel<<<dim3(gg, 2), 256, 0, stream>>>(g0a, g0p, n);
    gather_kernel<0><<<gw, 256, 0, stream>>>(c0a, c0p, offs, edge16, n);
    gemm_kernel<<<dim3(gg, 2), 256, 0, stream>>>(g1a, g1p, n);
    gather_kernel<1><<<gw, 256, 0, stream>>>(c1a, c1p, offs, edge16, n);
  } else {
    // sequential fallback: both halves run the same channel (duplicate
    // identical writes, benign); buffers aliased above.
    gemm_kernel<<<dim3(gg, 2), 256, 0, stream>>>(g0a, g0a, n);
    gather_kernel<0><<<gw, 256, 0, stream>>>(c0a, c0a, offs, edge16, n);
    gemm_kernel<<<dim3(gg, 2), 256, 0, stream>>>(g1a, g1a, n);
    gather_kernel<1><<<gw, 256, 0, stream>>>(c1a, c1a, offs, edge16, n);
    gemm_kernel<<<dim3(gg, 2), 256, 0, stream>>>(g0p, g0p, n);
    gather_kernel<0><<<gw, 256, 0, stream>>>(c0p, c0p, offs, edge16, n);
    gemm_kernel<<<dim3(gg, 2), 256, 0, stream>>>(g1p, g1p, n);
    gather_kernel<1><<<gw, 256, 0, stream>>>(c1p, c1p, offs, edge16, n);
  }
}

// Round 9
// 432.600 us; speedup vs baseline: 1.6811x; 1.0052x over previous
//
#include <hip/hip_runtime.h>
#include <hip/hip_fp16.h>

// ---------------------------------------------------------------------------
// DUPLEX GAT, round 9.
//   - dst-CSR build once (hist + parallel scan + fill; packed int4 edge recs).
//   - W prep: 4 weight mats -> fp16 Wt[n][k] (MFMA B-frags contiguous).
//   - Per layer (both channels per dispatch):
//       GEMM (MFMA f16, fp32 acc): 128x128 tile, two 64-wide K LDS phases;
//         A staged fp32->fp16 (layer 0) or raw fp16 (layer 1, hb is fp16);
//         epilogue: acc -> LDS fp16 -> coalesced ft + fused fp32 el/er dots.
//       gather: one wave per (node, channel); SCALAR-ADDRESSED inner loop:
//         uniform loop counter -> edge records via s_load; src in SGPR ->
//         ft/el loads use SGPR base + lane offset (~10 VALU/edge);
//         8 edges per batch in flight; redundant per-lane denominator.
//   ft fp16 everywhere on the gather path; hb (layer-0 out / layer-1 A) fp16
//   (GEMM-1 would fp16-quantize it anyway); el/er fp32.
// ---------------------------------------------------------------------------

typedef _Float16 f16x8 __attribute__((ext_vector_type(8)));
typedef float f32x4 __attribute__((ext_vector_type(4)));

struct GemmP { const void* X; const __half* Wt; const float *al, *ar; __half* Y; float *el, *er; };
struct ChP   { const __half* ft; const float *el, *er, *bias; void* out; };

__global__ void hist_kernel(const int* __restrict__ dst, int* __restrict__ counts, int E) {
  int e = blockIdx.x * blockDim.x + threadIdx.x;
  if (e < E) atomicAdd(&counts[dst[e]], 1);
}

__global__ __launch_bounds__(256) void scan1_kernel(const int* __restrict__ counts,
                                                    int* __restrict__ incl,
                                                    int* __restrict__ bsum, int n) {
  __shared__ int lds[256];
  int i = blockIdx.x * 256 + threadIdx.x;
  int v = (i < n) ? counts[i] : 0;
  lds[threadIdx.x] = v;
  __syncthreads();
  for (int off = 1; off < 256; off <<= 1) {
    int t = (threadIdx.x >= off) ? lds[threadIdx.x - off] : 0;
    __syncthreads();
    lds[threadIdx.x] += t;
    __syncthreads();
  }
  if (i < n) incl[i] = lds[threadIdx.x];
  if (threadIdx.x == 255) bsum[blockIdx.x] = lds[255];
}

__global__ __launch_bounds__(256) void scan2_kernel(int* __restrict__ bsum, int nb) {
  __shared__ int lds[256];
  int carry = 0;
  for (int base = 0; base < nb; base += 256) {
    int i = base + threadIdx.x;
    int v = (i < nb) ? bsum[i] : 0;
    lds[threadIdx.x] = v;
    __syncthreads();
    for (int off = 1; off < 256; off <<= 1) {
      int t = (threadIdx.x >= off) ? lds[threadIdx.x - off] : 0;
      __syncthreads();
      lds[threadIdx.x] += t;
      __syncthreads();
    }
    if (i < nb) bsum[i] = carry + lds[threadIdx.x] - v;  // exclusive
    carry += lds[255];
    __syncthreads();
  }
}

__global__ void scan3_kernel(const int* __restrict__ counts, const int* __restrict__ incl,
                             const int* __restrict__ bsum_ex, int* __restrict__ offsets,
                             int n, int E) {
  int i = blockIdx.x * blockDim.x + threadIdx.x;
  if (i < n) offsets[i] = incl[i] - counts[i] + bsum_ex[i >> 8];
  if (i == 0) offsets[n] = E;
}

__global__ void fill_kernel(const int* __restrict__ src, const int* __restrict__ dst,
                            const float* __restrict__ exist, const float* __restrict__ am_exist,
                            int* __restrict__ cursor, int4* __restrict__ edge16, int E) {
  int e = blockIdx.x * blockDim.x + threadIdx.x;
  if (e >= E) return;
  int pos = atomicAdd(&cursor[dst[e]], 1);
  edge16[pos] = make_int4(src[e], __float_as_int(am_exist[e]), __float_as_int(exist[e]), 0);
}

// Convert + transpose 4 weight matrices: Wt_m[nn][k] = (half)W_m[k][nn].
__global__ void wprep_kernel(const float* __restrict__ W0a, const float* __restrict__ W0p,
                             const float* __restrict__ W1a, const float* __restrict__ W1p,
                             __half* __restrict__ Wt) {
  int m = blockIdx.y;
  const float* W = (m == 0) ? W0a : (m == 1) ? W0p : (m == 2) ? W1a : W1p;
  __half* O = Wt + (size_t)m * 16384;
  int i = blockIdx.x * 256 + threadIdx.x;  // 0..16383
  int nn = i >> 7, k = i & 127;
  O[nn * 128 + k] = __float2half_rn(W[k * 128 + nn]);
}

// Y(fp16) = fp16(X) @ fp16(W), fp32 MFMA acc; fused fp32 el/er epilogue.
// AFP16: A operand already fp16 (layer 1) vs fp32->fp16 staging (layer 0).
template <int AFP16>
__global__ __launch_bounds__(256) void gemm_kernel(GemmP p0, GemmP p1, int n) {
  GemmP p = blockIdx.y ? p1 : p0;
  constexpr int LDH = 72;   // staging stride (halves)
  constexpr int LDE = 136;  // epilogue stride (halves)
  __shared__ __half lds[2 * 128 * LDH];  // 36,864 B
  __half* As = lds;
  __half* Ws = lds + 128 * LDH;
  int t = threadIdx.x;
  int row0 = blockIdx.x << 7;
  int wv = t >> 6, lane = t & 63;
  int m = lane & 15, q = lane >> 4;

  f32x4 acc[2][8];
#pragma unroll
  for (int rt = 0; rt < 2; ++rt)
#pragma unroll
    for (int ct = 0; ct < 8; ++ct) acc[rt][ct] = (f32x4){0.f, 0.f, 0.f, 0.f};

#pragma unroll
  for (int kh = 0; kh < 2; ++kh) {
    __syncthreads();  // protect previous phase's fragment reads
    if (AFP16) {
      const __half* Xh = (const __half*)p.X;
#pragma unroll
      for (int i = 0; i < 4; ++i) {
        int c = t + (i << 8);  // 0..1023 chunks of 8 halves
        int r = c >> 3, o8 = c & 7;
        uint4 v = make_uint4(0, 0, 0, 0);
        if (row0 + r < n)
          v = *(const uint4*)(Xh + (size_t)(row0 + r) * 128 + (kh << 6) + (o8 << 3));
        *(uint4*)(As + r * LDH + (o8 << 3)) = v;
      }
    } else {
      const float* Xf = (const float*)p.X;
#pragma unroll
      for (int i = 0; i < 8; ++i) {
        int c = t + (i << 8);  // 0..2047 float4-chunks
        int r = c >> 4, f4 = c & 15;
        float4 v = make_float4(0.f, 0.f, 0.f, 0.f);
        if (row0 + r < n)
          v = *(const float4*)(Xf + (size_t)(row0 + r) * 128 + (kh << 6) + (f4 << 2));
        union { __half h[4]; uint2 u; } pk;
        pk.h[0] = __float2half_rn(v.x); pk.h[1] = __float2half_rn(v.y);
        pk.h[2] = __float2half_rn(v.z); pk.h[3] = __float2half_rn(v.w);
        *(uint2*)(As + r * LDH + (f4 << 2)) = pk.u;
      }
    }
    // stage Wt: 128 n-rows x 64 k (already fp16)
#pragma unroll
    for (int i = 0; i < 4; ++i) {
      int c = t + (i << 8);
      int r = c >> 3, o8 = c & 7;
      uint4 v = *(const uint4*)(p.Wt + (size_t)r * 128 + (kh << 6) + (o8 << 3));
      *(uint4*)(Ws + r * LDH + (o8 << 3)) = v;
    }
    __syncthreads();
#pragma unroll
    for (int kc = 0; kc < 2; ++kc) {
      f16x8 a0 = *(const f16x8*)(As + (wv * 32 + m) * LDH + kc * 32 + q * 8);
      f16x8 a1 = *(const f16x8*)(As + (wv * 32 + 16 + m) * LDH + kc * 32 + q * 8);
#pragma unroll
      for (int ct = 0; ct < 8; ++ct) {
        f16x8 b = *(const f16x8*)(Ws + (ct * 16 + m) * LDH + kc * 32 + q * 8);
        acc[0][ct] = __builtin_amdgcn_mfma_f32_16x16x32_f16(a0, b, acc[0][ct], 0, 0, 0);
        acc[1][ct] = __builtin_amdgcn_mfma_f32_16x16x32_f16(a1, b, acc[1][ct], 0, 0, 0);
      }
    }
  }
  // ---- epilogue: acc -> LDS fp16 (C/D layout: col=lane&15, row=quad*4+reg) ----
  __syncthreads();
#pragma unroll
  for (int rt = 0; rt < 2; ++rt) {
    int rbase = wv * 32 + rt * 16 + q * 4;
#pragma unroll
    for (int ct = 0; ct < 8; ++ct) {
      int col = ct * 16 + m;
#pragma unroll
      for (int r = 0; r < 4; ++r)
        lds[(rbase + r) * LDE + col] = __float2half_rn(acc[rt][ct][r]);
    }
  }
  __syncthreads();
  // 2 threads per row: half = cols 0..63 / 64..127. ft store + el/er head-dots.
  {
    int r = t & 127;
    int half = t >> 7;
    int row = row0 + r;
    if (row < n) {
      float e0 = 0.f, e1 = 0.f, r0 = 0.f, r1 = 0.f;
#pragma unroll
      for (int i = 0; i < 8; ++i) {
        int cbase = half * 64 + i * 8;
        f16x8 v = *(const f16x8*)(lds + r * LDE + cbase);
        *(uint4*)(p.Y + (size_t)row * 128 + cbase) = *(const uint4*)&v;
#pragma unroll
        for (int j = 0; j < 8; ++j) {
          float f = (float)v[j];
          float av = p.al[cbase + j];
          float rv = p.ar[cbase + j];
          if (((i * 8 + j) >> 5) == 0) { e0 = fmaf(f, av, e0); r0 = fmaf(f, rv, r0); }
          else                         { e1 = fmaf(f, av, e1); r1 = fmaf(f, rv, r1); }
        }
      }
      *(float2*)(p.el + (size_t)row * 4 + half * 2) = make_float2(e0, e1);
      *(float2*)(p.er + (size_t)row * 4 + half * 2) = make_float2(r0, r1);
    }
  }
}

// One wave per (node, channel). Block = 4 waves = 2 nodes x 2 channels.
// Scalar-addressed inner loop: loop counter is uniform -> edge records load
// through the scalar pipe; src sits in an SGPR so ft/el loads are
// SGPR-base + lane-offset. Redundant per-lane denominator (no reduction).
template <int LAYER>
__global__ __launch_bounds__(256) void gather_kernel(ChP c0, ChP c1,
                                                     const int* __restrict__ offs,
                                                     const int4* __restrict__ edge16, int n) {
  int t = threadIdx.x;
  int w = t >> 6;
  int lane = t & 63;
  int node = blockIdx.x * 2 + (w >> 1);
  int ch = w & 1;
  if (node >= n) return;  // wave-uniform
  ChP P = ch ? c1 : c0;
  int hh = lane >> 4;

  int start = __builtin_amdgcn_readfirstlane(offs[node]);
  int end = __builtin_amdgcn_readfirstlane(offs[node + 1]);
  float er_h = P.er[(size_t)node * 4 + hh];
  const __half2* ftbase = (const __half2*)P.ft;
  const float* elbase = P.el;

  float acc0 = 0.f, acc1 = 0.f, l = 0.f;
  int k = start;
  while (k + 8 <= end) {
    int4 ed[8];
#pragma unroll
    for (int j = 0; j < 8; ++j) ed[j] = edge16[k + j];
#pragma unroll
    for (int j = 0; j < 8; ++j) {
      int s = ed[j].x;  // uniform -> SGPR
      float wgt = __int_as_float(ch ? ed[j].z : ed[j].y);
      float elv = (elbase + (size_t)s * 4)[hh];            // saddr + hh*4
      float2 f = __half22float2((ftbase + (size_t)s * 64)[lane]);  // saddr + lane*4
      float e = elv + er_h;
      e = (e > 0.f) ? e : 0.2f * e;
      float x = __expf(e);
      l += x;
      float cv = x * wgt;
      acc0 = fmaf(cv, f.x, acc0);
      acc1 = fmaf(cv, f.y, acc1);
    }
    k += 8;
  }
  for (; k < end; ++k) {
    int4 ed = edge16[k];
    int s = ed.x;
    float wgt = __int_as_float(ch ? ed.z : ed.y);
    float elv = (elbase + (size_t)s * 4)[hh];
    float2 f = __half22float2((ftbase + (size_t)s * 64)[lane]);
    float e = elv + er_h;
    e = (e > 0.f) ? e : 0.2f * e;
    float x = __expf(e);
    l += x;
    float cv = x * wgt;
    acc0 = fmaf(cv, f.x, acc0);
    acc1 = fmaf(cv, f.y, acc1);
  }

  float rl = 1.f / fmaxf(l, 1e-9f);
  float2 b2 = *(const float2*)(P.bias + lane * 2);
  float v0 = fmaf(acc0, rl, b2.x);
  float v1 = fmaf(acc1, rl, b2.y);
  if (LAYER == 0) {
    // fp16 hidden buffer (GEMM-1 would quantize to fp16 anyway)
    __half2 h = __floats2half2_rn(fmaxf(v0, 0.f), fmaxf(v1, 0.f));
    ((__half2*)P.out)[(size_t)node * 64 + lane] = h;
  } else {
    v0 += __shfl_xor(v0, 16); v1 += __shfl_xor(v1, 16);
    v0 += __shfl_xor(v0, 32); v1 += __shfl_xor(v1, 32);
    if (lane < 16) {
      *(float2*)((float*)P.out + (size_t)node * 32 + lane * 2) =
          make_float2(0.25f * v0, 0.25f * v1);
    }
  }
}

extern "C" void kernel_launch(void* const* d_in, const int* in_sizes, int n_in,
                              void* d_out, int out_size, void* d_ws, size_t ws_size,
                              hipStream_t stream) {
  const float* x_am = (const float*)d_in[0];
  const float* x_ph = (const float*)d_in[1];
  const float* exist = (const float*)d_in[2];
  const float* am_exist = (const float*)d_in[3];
  const int* src = (const int*)d_in[4];
  const int* dst = (const int*)d_in[5];
  const float* W0a = (const float*)d_in[6];
  const float* al0a = (const float*)d_in[7];
  const float* ar0a = (const float*)d_in[8];
  const float* b0a = (const float*)d_in[9];
  const float* W0p = (const float*)d_in[10];
  const float* al0p = (const float*)d_in[11];
  const float* ar0p = (const float*)d_in[12];
  const float* b0p = (const float*)d_in[13];
  const float* W1a = (const float*)d_in[14];
  const float* al1a = (const float*)d_in[15];
  const float* ar1a = (const float*)d_in[16];
  const float* b1a = (const float*)d_in[17];
  const float* W1p = (const float*)d_in[18];
  const float* al1p = (const float*)d_in[19];
  const float* ar1p = (const float*)d_in[20];
  const float* b1p = (const float*)d_in[21];

  int n = in_sizes[0] / 128;  // 50000
  int E = in_sizes[2];        // 800000
  int N_pad = (n + 255) & ~255;
  int nb = (n + 255) / 256;
  int NB_pad = (nb + 63) & ~63;

  size_t szN = (size_t)N_pad * 4;
  size_t szOffs = (size_t)(N_pad + 8) * 4;
  size_t szE16 = (size_t)E * 16;
  size_t szFt16 = (size_t)n * 128 * 2;  // fp16 ft / hb
  size_t szEl = (size_t)N_pad * 4 * 4;
  size_t szWt = (size_t)4 * 128 * 128 * 2;

  auto rnd = [](size_t b) { return (b + 255) & ~(size_t)255; };
  size_t fixed = 3 * rnd(szN) + rnd((size_t)NB_pad * 4) + rnd(szOffs) + rnd(szE16) +
                 4 * rnd(szEl) + rnd(szWt);
  bool dual = ws_size >= fixed + 4 * rnd(szFt16);

  char* p = (char*)d_ws;
  auto take = [&](size_t b) { char* q = p; p += (b + 255) & ~(size_t)255; return q; };
  int* counts = (int*)take(szN);
  int* cursor = (int*)take(szN);
  int* incl = (int*)take(szN);
  int* bsum = (int*)take((size_t)NB_pad * 4);
  int* offs = (int*)take(szOffs);
  int4* edge16 = (int4*)take(szE16);
  __half* Wt = (__half*)take(szWt);
  float* el_am = (float*)take(szEl);
  float* el_ph = (float*)take(szEl);
  float* er_am = (float*)take(szEl);
  float* er_ph = (float*)take(szEl);
  __half* ft_am = (__half*)take(szFt16);
  __half* ft_ph = dual ? (__half*)take(szFt16) : ft_am;
  __half* hb_am = (__half*)take(szFt16);
  __half* hb_ph = dual ? (__half*)take(szFt16) : hb_am;

  float* out_am = (float*)d_out;
  float* out_ph = out_am + (size_t)n * 32;

  // ---- CSR build + weight prep ----
  hipMemsetAsync(counts, 0, szN, stream);
  hist_kernel<<<(E + 255) / 256, 256, 0, stream>>>(dst, counts, E);
  wprep_kernel<<<dim3(64, 4), 256, 0, stream>>>(W0a, W0p, W1a, W1p, Wt);
  scan1_kernel<<<nb, 256, 0, stream>>>(counts, incl, bsum, n);
  scan2_kernel<<<1, 256, 0, stream>>>(bsum, nb);
  scan3_kernel<<<nb, 256, 0, stream>>>(counts, incl, bsum, offs, n, E);
  hipMemcpyAsync(cursor, offs, szN, hipMemcpyDeviceToDevice, stream);
  fill_kernel<<<(E + 255) / 256, 256, 0, stream>>>(src, dst, exist, am_exist,
                                                   cursor, edge16, E);

  int gg = (n + 127) / 128;
  int gw = (n + 1) / 2;
  GemmP g0a{x_am, Wt,          al0a, ar0a, ft_am, el_am, er_am};
  GemmP g0p{x_ph, Wt + 16384,  al0p, ar0p, ft_ph, el_ph, er_ph};
  GemmP g1a{hb_am, Wt + 32768, al1a, ar1a, ft_am, el_am, er_am};
  GemmP g1p{hb_ph, Wt + 49152, al1p, ar1p, ft_ph, el_ph, er_ph};
  ChP c0a{ft_am, el_am, er_am, b0a, hb_am};
  ChP c0p{ft_ph, el_ph, er_ph, b0p, hb_ph};
  ChP c1a{ft_am, el_am, er_am, b1a, out_am};
  ChP c1p{ft_ph, el_ph, er_ph, b1p, out_ph};

  if (dual) {
    gemm_kernel<0><<<dim3(gg, 2), 256, 0, stream>>>(g0a, g0p, n);
    gather_kernel<0><<<gw, 256, 0, stream>>>(c0a, c0p, offs, edge16, n);
    gemm_kernel<1><<<dim3(gg, 2), 256, 0, stream>>>(g1a, g1p, n);
    gather_kernel<1><<<gw, 256, 0, stream>>>(c1a, c1p, offs, edge16, n);
  } else {
    // sequential fallback: both halves run the same channel (duplicate
    // identical writes, benign); buffers aliased above.
    gemm_kernel<0><<<dim3(gg, 2), 256, 0, stream>>>(g0a, g0a, n);
    gather_kernel<0><<<gw, 256, 0, stream>>>(c0a, c0a, offs, edge16, n);
    gemm_kernel<1><<<dim3(gg, 2), 256, 0, stream>>>(g1a, g1a, n);
    gather_kernel<1><<<gw, 256, 0, stream>>>(c1a, c1a, offs, edge16, n);
    gemm_kernel<0><<<dim3(gg, 2), 256, 0, stream>>>(g0p, g0p, n);
    gather_kernel<0><<<gw, 256, 0, stream>>>(c0p, c0p, offs, edge16, n);
    gemm_kernel<1><<<dim3(gg, 2), 256, 0, stream>>>(g1p, g1p, n);
    gather_kernel<1><<<gw, 256, 0, stream>>>(c1p, c1p, offs, edge16, n);
  }
}